// Round 1
// 496.043 us; speedup vs baseline: 1.0139x; 1.0139x over previous
//
#include <hip/hip_runtime.h>
#include <hip/hip_bf16.h>

#define HEADS 8
#define DIM 128

typedef short s8v __attribute__((ext_vector_type(8)));
typedef float f4v __attribute__((ext_vector_type(4)));

__device__ __forceinline__ float bf2f(unsigned int lo16) {
    union { unsigned int i; float f; } v; v.i = lo16 << 16; return v.f;
}
__device__ __forceinline__ unsigned short f2bf(float f) {
    __hip_bfloat16 h = __float2bfloat16(f);
    return *reinterpret_cast<unsigned short*>(&h);
}
__device__ __forceinline__ int imin(int a, int b) { return a < b ? a : b; }

// DPP butterfly add within 8-lane groups (head groups). CTRL must be imm.
// 0xB1 = quad_perm(1,0,3,2) = xor1; 0x4E = quad_perm(2,3,0,1) = xor2;
// 0x141 = row_half_mirror = lane^7 within each 8-lane half-row.
template<int CTRL>
__device__ __forceinline__ float dpp_add_f(float x) {
    int y = __builtin_amdgcn_update_dpp(0, __float_as_int(x), CTRL, 0xF, 0xF, true);
    return x + __int_as_float(y);
}

#if __has_builtin(__builtin_amdgcn_exp2f)
#define fast_exp2(x) __builtin_amdgcn_exp2f(x)
#else
#define fast_exp2(x) __expf(0.6931471805599453f * (x))
#endif

// ---------------------------------------------------------------------------
// Fused setup: per-block dtype sniff (int64 vs int32) + edge convert + degree
// count. Every block redundantly sniffs the first 2 KB (validated logic, R2).
// ---------------------------------------------------------------------------
__global__ __launch_bounds__(256) void setup_k(const void* __restrict__ ei, int n2, int E,
                                               int* __restrict__ out, int* __restrict__ deg) {
    __shared__ int cnt;
    const unsigned int* w = (const unsigned int*)ei;
    if (threadIdx.x == 0) cnt = 0;
    __syncthreads();
    if (w[2 * threadIdx.x + 1] == 0u) atomicAdd(&cnt, 1);
    __syncthreads();
    const bool is64 = cnt > 192;
    int i = blockIdx.x * 256 + threadIdx.x;
    if (i < n2) {
        int v = is64 ? (int)((const long long*)ei)[i] : ((const int*)ei)[i];
        out[i] = v;
        if (i < E) atomicAdd(&deg[v], 1);   // rows half
    }
}

// ---------------------------------------------------------------------------
// CSR scan + scatter (validated in R2)
// ---------------------------------------------------------------------------
__global__ void scan1_k(const int* __restrict__ deg, int n,
                        int* __restrict__ incl, int* __restrict__ blkSums) {
    __shared__ int s[256];
    int i = blockIdx.x * 256 + threadIdx.x;
    int v = (i < n) ? deg[i] : 0;
    s[threadIdx.x] = v;
    __syncthreads();
    for (int off = 1; off < 256; off <<= 1) {
        int t = (threadIdx.x >= off) ? s[threadIdx.x - off] : 0;
        __syncthreads();
        s[threadIdx.x] += t;
        __syncthreads();
    }
    if (i < n) incl[i] = s[threadIdx.x];
    if (threadIdx.x == 255) blkSums[blockIdx.x] = s[255];
}

__global__ void scan2_k(int* __restrict__ blkSums, int nb) {
    __shared__ int s[256];
    int v = (threadIdx.x < nb) ? blkSums[threadIdx.x] : 0;
    s[threadIdx.x] = v;
    __syncthreads();
    for (int off = 1; off < 256; off <<= 1) {
        int t = (threadIdx.x >= off) ? s[threadIdx.x - off] : 0;
        __syncthreads();
        s[threadIdx.x] += t;
        __syncthreads();
    }
    if (threadIdx.x < nb) blkSums[threadIdx.x] = s[threadIdx.x] - v;
}

__global__ void scan3_k(const int* __restrict__ incl, const int* __restrict__ deg,
                        const int* __restrict__ blkOff, int n,
                        int* __restrict__ rowPtr, int* __restrict__ cursor) {
    int i = blockIdx.x * 256 + threadIdx.x;
    if (i < n) {
        int inc = incl[i] + blkOff[blockIdx.x];
        rowPtr[i + 1] = inc;
        cursor[i] = inc - deg[i];
    }
    if (i == 0) rowPtr[0] = 0;
}

__global__ void scatter_k(const int* __restrict__ rows, const int* __restrict__ cols, int E,
                          int* __restrict__ cursor, int* __restrict__ colIdx) {
    int e = blockIdx.x * 256 + threadIdx.x;
    if (e < E) {
        int pos = atomicAdd(&cursor[rows[e]], 1);
        colIdx[pos] = cols[e];
    }
}

// ---------------------------------------------------------------------------
// All weight-fragment builds in ONE kernel; job table by blockIdx.
// Frag f = (comp*split + p)*perPhase + (nt*KS + ks)*64 + lane; element j =
// W[ks*32 + (lane>>4)*8 + j][p*(Nd/split) + nt*16 + (lane&15)]. hi/lo bf16.
// ---------------------------------------------------------------------------
__global__ __launch_bounds__(256) void build_all_wfrag_k(
    const float* __restrict__ Wp, const float* __restrict__ q1, const float* __restrict__ k1,
    const float* __restrict__ v1, const float* __restrict__ q2, const float* __restrict__ k2,
    const float* __restrict__ v2, const float* __restrict__ invw,
    unsigned short* __restrict__ wfragP, unsigned short* __restrict__ wfragQKV1,
    unsigned short* __restrict__ wfragQKV2, unsigned short* __restrict__ wfragO)
{
    const int b = blockIdx.x;
    const float* W; unsigned short* dst; int Kd, Nd, ncomp, fb;
    const int split = 2;
    if (b < 32) { W = Wp; dst = wfragP; Kd = 256; Nd = 128; ncomp = 2; fb = b; }
    else if (b < 128) {
        int j = (b - 32) >> 4, r = (b - 32) & 15;
        const float* ws[6] = { q1, k1, v1, q2, k2, v2 };
        W = ws[j];
        dst = ((j < 3) ? wfragQKV1 : wfragQKV2) + (size_t)(j % 3) * 2 * 128 * 128;
        Kd = 128; Nd = 128; ncomp = 2; fb = r;
    } else { W = invw; dst = wfragO; Kd = 128; Nd = 256; ncomp = 1; fb = b - 128; }

    int f = fb * 256 + threadIdx.x;
    int KS = Kd >> 5;
    int perPhase = (Nd / 16 / split) * KS * 64;
    if (f >= ncomp * split * perPhase) return;
    int comp = f / (split * perPhase);
    int r1 = f - comp * split * perPhase;
    int p = r1 / perPhase;
    int r = r1 - p * perPhase;
    int nt = r / (KS * 64);
    int r2 = r - nt * KS * 64;
    int ks = r2 >> 6, lane = r2 & 63;
    int n = p * (Nd / split) + nt * 16 + (lane & 15);
    int k0 = ks * 32 + (lane >> 4) * 8;
    unsigned short tmp[8];
#pragma unroll
    for (int j = 0; j < 8; j++) {
        float w = W[(size_t)(k0 + j) * Nd + n];
        unsigned short hi = f2bf(w);
        tmp[j] = (comp == 0) ? hi : f2bf(w - bf2f(hi));
    }
#pragma unroll
    for (int j = 0; j < 8; j++) dst[(size_t)f * 8 + j] = tmp[j];
}

// ---------------------------------------------------------------------------
// Input projection (LDS-free): trunk planes = x(f32)[M,256] @ W_P + b + pos.
// grid (391,2): blockIdx.y = 64-col phase. 256 thr = 4 waves, 1 row-pair each.
// B-frags read wave-coalesced from global (L2-resident). Ah*Bh+Ah*Bl+Al*Bh.
// ---------------------------------------------------------------------------
__global__ __launch_bounds__(256) void proj_k(
    const float* __restrict__ A, const unsigned short* __restrict__ wfrag,
    const float* __restrict__ b0, const float* __restrict__ b1,
    unsigned short* __restrict__ ehi, unsigned short* __restrict__ elo, int M)
{
    constexpr int KD = 256, KS = 8, NTp = 4;
    constexpr int FRp = NTp * KS * 64;  // 2048
    const int lane = threadIdx.x & 63;
    const int m16 = lane & 15, q4 = lane >> 4;
    const int phase = blockIdx.y;
    const int pairIdx = blockIdx.x * 4 + (threadIdx.x >> 6);
    const int nPairs = (M + 31) >> 5;
    if (pairIdx >= nPairs) return;

    const int row0 = pairIdx * 32;
    const int rA0 = imin(row0 + m16, M - 1);
    const int rA1 = imin(row0 + 16 + m16, M - 1);

    f4v acc0[NTp], acc1[NTp];
#pragma unroll
    for (int nt = 0; nt < NTp; nt++) { acc0[nt] = (f4v){0,0,0,0}; acc1[nt] = (f4v){0,0,0,0}; }

    for (int ks = 0; ks < KS; ks++) {
        const f4v* pa0 = (const f4v*)(A + (size_t)rA0 * KD + ks * 32 + q4 * 8);
        const f4v* pa1 = (const f4v*)(A + (size_t)rA1 * KD + ks * 32 + q4 * 8);
        f4v xa = pa0[0], xb = pa0[1], ya = pa1[0], yb = pa1[1];
        s8v a0h, a0l, a1h, a1l;
#pragma unroll
        for (int j = 0; j < 4; j++) {
            unsigned short h;
            h = f2bf(xa[j]); a0h[j] = (short)h; a0l[j] = (short)f2bf(xa[j] - bf2f(h));
            h = f2bf(xb[j]); a0h[4 + j] = (short)h; a0l[4 + j] = (short)f2bf(xb[j] - bf2f(h));
            h = f2bf(ya[j]); a1h[j] = (short)h; a1l[j] = (short)f2bf(ya[j] - bf2f(h));
            h = f2bf(yb[j]); a1h[4 + j] = (short)h; a1l[4 + j] = (short)f2bf(yb[j] - bf2f(h));
        }
#pragma unroll
        for (int nt = 0; nt < NTp; nt++) {
            const size_t fi = ((size_t)(nt * KS + ks) * 64 + lane) * 8;
            s8v bh = *(const s8v*)(wfrag + ((size_t)(0 * 2 + phase) * FRp) * 8 + fi);
            s8v bl = *(const s8v*)(wfrag + ((size_t)(1 * 2 + phase) * FRp) * 8 + fi);
            acc0[nt] = __builtin_amdgcn_mfma_f32_16x16x32_bf16(a0h, bh, acc0[nt], 0, 0, 0);
            acc0[nt] = __builtin_amdgcn_mfma_f32_16x16x32_bf16(a0h, bl, acc0[nt], 0, 0, 0);
            acc0[nt] = __builtin_amdgcn_mfma_f32_16x16x32_bf16(a0l, bh, acc0[nt], 0, 0, 0);
            acc1[nt] = __builtin_amdgcn_mfma_f32_16x16x32_bf16(a1h, bh, acc1[nt], 0, 0, 0);
            acc1[nt] = __builtin_amdgcn_mfma_f32_16x16x32_bf16(a1h, bl, acc1[nt], 0, 0, 0);
            acc1[nt] = __builtin_amdgcn_mfma_f32_16x16x32_bf16(a1l, bh, acc1[nt], 0, 0, 0);
        }
    }

#pragma unroll
    for (int nt = 0; nt < NTp; nt++) {
        const int col = phase * 64 + nt * 16 + m16;
        const float bias = b0[col] + b1[col];
#pragma unroll
        for (int r = 0; r < 4; r++) {
            const int gr0 = row0 + q4 * 4 + r;
            if (gr0 < M) {
                float v = acc0[nt][r] + bias;
                unsigned short h = f2bf(v);
                ehi[(size_t)gr0 * DIM + col] = h;
                elo[(size_t)gr0 * DIM + col] = f2bf(v - bf2f(h));
            }
            const int gr1 = gr0 + 16;
            if (gr1 < M && row0 + 16 < M) {
                float v = acc1[nt][r] + bias;
                unsigned short h = f2bf(v);
                ehi[(size_t)gr1 * DIM + col] = h;
                elo[(size_t)gr1 * DIM + col] = f2bf(v - bf2f(h));
            }
        }
    }
}

// ---------------------------------------------------------------------------
// Fused QKV (LDS-free): A = trunk planes. Q f32 (split-precision), K,V bf16
// interleaved KV[M][256]. grid (391,2).
// ---------------------------------------------------------------------------
__global__ __launch_bounds__(256) void qkv_k(
    const unsigned short* __restrict__ ehi, const unsigned short* __restrict__ elo,
    const unsigned short* __restrict__ wfrag,
    float* __restrict__ Qb, unsigned short* __restrict__ KVb, int M)
{
    constexpr int KS = 4, NTp = 4;
    constexpr int FRp = NTp * KS * 64;   // 1024
    constexpr int MATFR = 4 * FRp;       // 2 comp x 2 phase
    const int lane = threadIdx.x & 63;
    const int m16 = lane & 15, q4 = lane >> 4;
    const int phase = blockIdx.y;
    const int pairIdx = blockIdx.x * 4 + (threadIdx.x >> 6);
    const int nPairs = (M + 31) >> 5;
    if (pairIdx >= nPairs) return;

    const int row0 = pairIdx * 32;
    const int rA0 = imin(row0 + m16, M - 1);
    const int rA1 = imin(row0 + 16 + m16, M - 1);

    s8v a0h[KS], a0l[KS], a1h[KS], a1l[KS];
#pragma unroll
    for (int ks = 0; ks < KS; ks++) {
        a0h[ks] = *(const s8v*)(ehi + (size_t)rA0 * DIM + ks * 32 + q4 * 8);
        a0l[ks] = *(const s8v*)(elo + (size_t)rA0 * DIM + ks * 32 + q4 * 8);
        a1h[ks] = *(const s8v*)(ehi + (size_t)rA1 * DIM + ks * 32 + q4 * 8);
        a1l[ks] = *(const s8v*)(elo + (size_t)rA1 * DIM + ks * 32 + q4 * 8);
    }

    f4v aQ0[NTp], aQ1[NTp], aK0[NTp], aK1[NTp], aV0[NTp], aV1[NTp];
#pragma unroll
    for (int nt = 0; nt < NTp; nt++) {
        aQ0[nt] = (f4v){0,0,0,0}; aQ1[nt] = (f4v){0,0,0,0};
        aK0[nt] = (f4v){0,0,0,0}; aK1[nt] = (f4v){0,0,0,0};
        aV0[nt] = (f4v){0,0,0,0}; aV1[nt] = (f4v){0,0,0,0};
    }

#pragma unroll
    for (int ks = 0; ks < KS; ks++) {
#pragma unroll
        for (int nt = 0; nt < NTp; nt++) {
            const size_t fi = ((size_t)(nt * KS + ks) * 64 + lane) * 8;
            s8v qh = *(const s8v*)(wfrag + (size_t)(0 * MATFR + (0 * 2 + phase) * FRp) * 8 + fi);
            s8v ql = *(const s8v*)(wfrag + (size_t)(0 * MATFR + (1 * 2 + phase) * FRp) * 8 + fi);
            s8v kh = *(const s8v*)(wfrag + (size_t)(1 * MATFR + (0 * 2 + phase) * FRp) * 8 + fi);
            s8v kl = *(const s8v*)(wfrag + (size_t)(1 * MATFR + (1 * 2 + phase) * FRp) * 8 + fi);
            s8v vh = *(const s8v*)(wfrag + (size_t)(2 * MATFR + (0 * 2 + phase) * FRp) * 8 + fi);
            aQ0[nt] = __builtin_amdgcn_mfma_f32_16x16x32_bf16(a0h[ks], qh, aQ0[nt], 0, 0, 0);
            aQ0[nt] = __builtin_amdgcn_mfma_f32_16x16x32_bf16(a0h[ks], ql, aQ0[nt], 0, 0, 0);
            aQ0[nt] = __builtin_amdgcn_mfma_f32_16x16x32_bf16(a0l[ks], qh, aQ0[nt], 0, 0, 0);
            aQ1[nt] = __builtin_amdgcn_mfma_f32_16x16x32_bf16(a1h[ks], qh, aQ1[nt], 0, 0, 0);
            aQ1[nt] = __builtin_amdgcn_mfma_f32_16x16x32_bf16(a1h[ks], ql, aQ1[nt], 0, 0, 0);
            aQ1[nt] = __builtin_amdgcn_mfma_f32_16x16x32_bf16(a1l[ks], qh, aQ1[nt], 0, 0, 0);
            aK0[nt] = __builtin_amdgcn_mfma_f32_16x16x32_bf16(a0h[ks], kh, aK0[nt], 0, 0, 0);
            aK0[nt] = __builtin_amdgcn_mfma_f32_16x16x32_bf16(a0h[ks], kl, aK0[nt], 0, 0, 0);
            aK0[nt] = __builtin_amdgcn_mfma_f32_16x16x32_bf16(a0l[ks], kh, aK0[nt], 0, 0, 0);
            aK1[nt] = __builtin_amdgcn_mfma_f32_16x16x32_bf16(a1h[ks], kh, aK1[nt], 0, 0, 0);
            aK1[nt] = __builtin_amdgcn_mfma_f32_16x16x32_bf16(a1h[ks], kl, aK1[nt], 0, 0, 0);
            aK1[nt] = __builtin_amdgcn_mfma_f32_16x16x32_bf16(a1l[ks], kh, aK1[nt], 0, 0, 0);
            aV0[nt] = __builtin_amdgcn_mfma_f32_16x16x32_bf16(a0h[ks], vh, aV0[nt], 0, 0, 0);
            aV0[nt] = __builtin_amdgcn_mfma_f32_16x16x32_bf16(a0l[ks], vh, aV0[nt], 0, 0, 0);
            aV1[nt] = __builtin_amdgcn_mfma_f32_16x16x32_bf16(a1h[ks], vh, aV1[nt], 0, 0, 0);
            aV1[nt] = __builtin_amdgcn_mfma_f32_16x16x32_bf16(a1l[ks], vh, aV1[nt], 0, 0, 0);
        }
    }

#pragma unroll
    for (int nt = 0; nt < NTp; nt++) {
        const int col = phase * 64 + nt * 16 + m16;
#pragma unroll
        for (int r = 0; r < 4; r++) {
            const int gr0 = row0 + q4 * 4 + r;
            if (gr0 < M) {
                Qb[(size_t)gr0 * DIM + col] = aQ0[nt][r];
                KVb[(size_t)gr0 * 256 + col] = f2bf(aK0[nt][r]);
                KVb[(size_t)gr0 * 256 + 128 + col] = f2bf(aV0[nt][r]);
            }
            const int gr1 = gr0 + 16;
            if (gr1 < M && row0 + 16 < M) {
                Qb[(size_t)gr1 * DIM + col] = aQ1[nt][r];
                KVb[(size_t)gr1 * 256 + col] = f2bf(aK1[nt][r]);
                KVb[(size_t)gr1 * 256 + 128 + col] = f2bf(aV1[nt][r]);
            }
        }
    }
}

// ---------------------------------------------------------------------------
// Output projection (LDS-free): d_out(f32)[M,256] = trunk @ inv_w + inv_b.
// ---------------------------------------------------------------------------
__global__ __launch_bounds__(256) void outproj_k(
    const unsigned short* __restrict__ ehi, const unsigned short* __restrict__ elo,
    const unsigned short* __restrict__ wfrag, const float* __restrict__ b0,
    float* __restrict__ Out, int M)
{
    constexpr int KS = 4, NTp = 8, NOUT = 256;
    constexpr int FRp = NTp * KS * 64;  // 2048
    const int lane = threadIdx.x & 63;
    const int m16 = lane & 15, q4 = lane >> 4;
    const int phase = blockIdx.y;
    const int pairIdx = blockIdx.x * 4 + (threadIdx.x >> 6);
    const int nPairs = (M + 31) >> 5;
    if (pairIdx >= nPairs) return;

    const int row0 = pairIdx * 32;
    const int rA0 = imin(row0 + m16, M - 1);
    const int rA1 = imin(row0 + 16 + m16, M - 1);

    s8v a0h[KS], a0l[KS], a1h[KS], a1l[KS];
#pragma unroll
    for (int ks = 0; ks < KS; ks++) {
        a0h[ks] = *(const s8v*)(ehi + (size_t)rA0 * DIM + ks * 32 + q4 * 8);
        a0l[ks] = *(const s8v*)(elo + (size_t)rA0 * DIM + ks * 32 + q4 * 8);
        a1h[ks] = *(const s8v*)(ehi + (size_t)rA1 * DIM + ks * 32 + q4 * 8);
        a1l[ks] = *(const s8v*)(elo + (size_t)rA1 * DIM + ks * 32 + q4 * 8);
    }

    f4v acc0[NTp], acc1[NTp];
#pragma unroll
    for (int nt = 0; nt < NTp; nt++) { acc0[nt] = (f4v){0,0,0,0}; acc1[nt] = (f4v){0,0,0,0}; }

#pragma unroll
    for (int ks = 0; ks < KS; ks++) {
#pragma unroll
        for (int nt = 0; nt < NTp; nt++) {
            s8v b = *(const s8v*)(wfrag + ((size_t)phase * FRp + (size_t)(nt * KS + ks) * 64 + lane) * 8);
            acc0[nt] = __builtin_amdgcn_mfma_f32_16x16x32_bf16(a0h[ks], b, acc0[nt], 0, 0, 0);
            acc0[nt] = __builtin_amdgcn_mfma_f32_16x16x32_bf16(a0l[ks], b, acc0[nt], 0, 0, 0);
            acc1[nt] = __builtin_amdgcn_mfma_f32_16x16x32_bf16(a1h[ks], b, acc1[nt], 0, 0, 0);
            acc1[nt] = __builtin_amdgcn_mfma_f32_16x16x32_bf16(a1l[ks], b, acc1[nt], 0, 0, 0);
        }
    }

#pragma unroll
    for (int nt = 0; nt < NTp; nt++) {
        const int col = phase * 128 + nt * 16 + m16;
        const float bias = b0[col];
#pragma unroll
        for (int r = 0; r < 4; r++) {
            const int gr0 = row0 + q4 * 4 + r;
            if (gr0 < M) Out[(size_t)gr0 * NOUT + col] = acc0[nt][r] + bias;
            const int gr1 = gr0 + 16;
            if (gr1 < M && row0 + 16 < M) Out[(size_t)gr1 * NOUT + col] = acc1[nt][r] + bias;
        }
    }
}

// ---------------------------------------------------------------------------
// Fused attention + residual + LayerNorm. One wave per node; lane owns dims
// (2*lane, 2*lane+1); head = lane>>3. 4-edge chunks, double-buffered prefetch
// (8 loads in flight). Q f32; KV interleaved bf16; trunk hi/lo bf16 planes.
// R-next: 8-lane score reduce via DPP adds (xor1/xor2/half_mirror) instead of
// ds_bpermute shuffles; q pre-scaled by log2e so softmax uses raw v_exp_f32
// (2^x domain; clamp bounds scaled accordingly).
// ---------------------------------------------------------------------------
__global__ __launch_bounds__(256) void agg_k(
    const float* __restrict__ Q, const unsigned short* __restrict__ KV,
    const int* __restrict__ rowPtr, const int* __restrict__ colIdx,
    const float* __restrict__ ln_s, const float* __restrict__ ln_b,
    unsigned short* __restrict__ ehi, unsigned short* __restrict__ elo, int n)
{
    const int node = blockIdx.x * 4 + (threadIdx.x >> 6);
    if (node >= n) return;
    const int lane = threadIdx.x & 63;
    const int d = lane * 2;

    constexpr float LOG2E = 1.4426950408889634f;
    constexpr float CLAMP = 10.0f * LOG2E;   // clip(t,±10) in 2^x domain

    const float2 qraw = *(const float2*)(Q + (size_t)node * DIM + d);
    const float qx = qraw.x * LOG2E, qy = qraw.y * LOG2E;
    const unsigned int rh = *(const unsigned int*)(ehi + (size_t)node * DIM + d);
    const unsigned int rl = *(const unsigned int*)(elo + (size_t)node * DIM + d);
    const float r0 = bf2f(rh & 0xffffu) + bf2f(rl & 0xffffu);
    const float r1 = bf2f(rh >> 16) + bf2f(rl >> 16);

    const int e0 = rowPtr[node], e1 = rowPtr[node + 1];
    float acc0 = 0.f, acc1 = 0.f, den = 0.f;

    if (e1 > e0) {
        unsigned int kA[4], vA[4], kB[4], vB[4];
#define LOADC(karr, varr, base_)                                        \
        {                                                               \
            _Pragma("unroll")                                           \
            for (int j = 0; j < 4; j++) {                               \
                int idx = (base_) + j;                                  \
                int cc = colIdx[idx < e1 ? idx : e1 - 1];               \
                size_t off = (size_t)cc * 256 + d;                      \
                karr[j] = *(const unsigned int*)(KV + off);             \
                varr[j] = *(const unsigned int*)(KV + off + 128);       \
            }                                                           \
        }
#define COMP(karr, varr, base_)                                         \
        {                                                               \
            _Pragma("unroll")                                           \
            for (int j = 0; j < 4; j++) {                               \
                if ((base_) + j < e1) {                                 \
                    float p = qx * bf2f(karr[j] & 0xffffu)              \
                            + qy * bf2f(karr[j] >> 16);                 \
                    p = dpp_add_f<0xB1>(p);   /* xor1 */                \
                    p = dpp_add_f<0x4E>(p);   /* xor2 */                \
                    p = dpp_add_f<0x141>(p);  /* ^7: other quad sum */  \
                    p = fminf(fmaxf(p, -CLAMP), CLAMP);                 \
                    float w = fast_exp2(p);                             \
                    den += w;                                           \
                    acc0 += w * bf2f(varr[j] & 0xffffu);                \
                    acc1 += w * bf2f(varr[j] >> 16);                    \
                }                                                       \
            }                                                           \
        }
        int base = e0;
        LOADC(kA, vA, base)
        while (base < e1) {
            int nxt = base + 4;
            if (nxt < e1) LOADC(kB, vB, nxt)
            COMP(kA, vA, base)
            base = nxt;
            if (base >= e1) break;
            int nxt2 = base + 4;
            if (nxt2 < e1) LOADC(kA, vA, nxt2)
            COMP(kB, vB, base)
            base = nxt2;
        }
#undef LOADC
#undef COMP
    }
    const float inv = 1.f / (den + 1e-8f);
    const float o0 = acc0 * inv + r0;
    const float o1 = acc1 * inv + r1;

    float s = o0 + o1, s2 = o0 * o0 + o1 * o1;
#pragma unroll
    for (int m = 1; m < 64; m <<= 1) {
        s  += __shfl_xor(s, m);
        s2 += __shfl_xor(s2, m);
    }
    const float mu = s * (1.f / 128.f);
    const float var = s2 * (1.f / 128.f) - mu * mu;
    const float rs = rsqrtf(var + 1e-6f);
    const float y0 = (o0 - mu) * rs * ln_s[d] + ln_b[d];
    const float y1 = (o1 - mu) * rs * ln_s[d + 1] + ln_b[d + 1];
    const unsigned short h0 = f2bf(y0), h1 = f2bf(y1);
    const unsigned short l0 = f2bf(y0 - bf2f(h0)), l1 = f2bf(y1 - bf2f(h1));
    *(unsigned int*)(ehi + (size_t)node * DIM + d) = (unsigned int)h0 | ((unsigned int)h1 << 16);
    *(unsigned int*)(elo + (size_t)node * DIM + d) = (unsigned int)l0 | ((unsigned int)l1 << 16);
}

// ---------------------------------------------------------------------------
// Launch
// ---------------------------------------------------------------------------
extern "C" void kernel_launch(void* const* d_in, const int* in_sizes, int n_in,
                              void* d_out, int out_size, void* d_ws, size_t ws_size,
                              hipStream_t stream)
{
    const float* x    = (const float*)d_in[0];
    const void*  ei   = d_in[1];
    const float* Wp   = (const float*)d_in[2];
    const float* Wpb  = (const float*)d_in[3];
    const float* Wpos = (const float*)d_in[4];
    const float* q1   = (const float*)d_in[5];
    const float* k1   = (const float*)d_in[6];
    const float* v1   = (const float*)d_in[7];
    const float* l1s  = (const float*)d_in[8];
    const float* l1b  = (const float*)d_in[9];
    const float* q2   = (const float*)d_in[10];
    const float* k2   = (const float*)d_in[11];
    const float* v2   = (const float*)d_in[12];
    const float* l2s  = (const float*)d_in[13];
    const float* l2b  = (const float*)d_in[14];
    const float* invw = (const float*)d_in[15];
    const float* invb = (const float*)d_in[16];

    const int N = in_sizes[0] / 256;   // 50000
    const int E = in_sizes[1] / 2;     // 800000

    char* p = (char*)d_ws;
    auto carve = [&](size_t bytes) -> void* {
        void* r = (void*)p;
        p += (bytes + 255) & ~(size_t)255;
        return r;
    };
    unsigned short* ehi = (unsigned short*)carve((size_t)N * DIM * 2);
    unsigned short* elo = (unsigned short*)carve((size_t)N * DIM * 2);
    float*          Qb  = (float*)carve((size_t)N * DIM * 4);
    unsigned short* KVb = (unsigned short*)carve((size_t)N * 256 * 2);
    int*   deg    = (int*)carve((size_t)N * 4);
    int*   incl   = (int*)carve((size_t)N * 4);
    int*   blkS   = (int*)carve(1024);
    int*   rowPtr = (int*)carve((size_t)(N + 1) * 4);
    int*   cursor = (int*)carve((size_t)N * 4);
    int*   colIdx = (int*)carve((size_t)E * 4);
    int*   rc     = (int*)carve((size_t)2 * E * 4);
    unsigned short* wfragP    = (unsigned short*)carve((size_t)2 * 256 * 128 * 2);
    unsigned short* wfragQKV1 = (unsigned short*)carve((size_t)3 * 2 * 128 * 128 * 2);
    unsigned short* wfragQKV2 = (unsigned short*)carve((size_t)3 * 2 * 128 * 128 * 2);
    unsigned short* wfragO    = (unsigned short*)carve((size_t)128 * 256 * 2);

    int* rows = rc;
    int* cols = rc + E;

    const int nb  = (N + 255) / 256;
    const int ebl = (E + 255) / 256;
    const int nPairs = (N + 31) / 32;
    const dim3 ggrid((nPairs + 3) / 4, 2);

    // CSR build (fused setup: dtype sniff + convert + degree count)
    hipMemsetAsync(deg, 0, (size_t)N * 4, stream);
    setup_k<<<(2 * E + 255) / 256, 256, 0, stream>>>(ei, 2 * E, E, rc, deg);
    scan1_k<<<nb, 256, 0, stream>>>(deg, N, incl, blkS);
    scan2_k<<<1, 256, 0, stream>>>(blkS, nb);
    scan3_k<<<nb, 256, 0, stream>>>(incl, deg, blkS, N, rowPtr, cursor);
    scatter_k<<<ebl, 256, 0, stream>>>(rows, cols, E, cursor, colIdx);

    // all weight fragments in one launch
    build_all_wfrag_k<<<144, 256, 0, stream>>>(Wp, q1, k1, v1, q2, k2, v2, invw,
                                               wfragP, wfragQKV1, wfragQKV2, wfragO);

    // input projection -> trunk planes
    proj_k<<<ggrid, 256, 0, stream>>>(x, wfragP, Wpb, Wpos, ehi, elo, N);

    // layer 1
    qkv_k<<<ggrid, 256, 0, stream>>>(ehi, elo, wfragQKV1, Qb, KVb, N);
    agg_k<<<(N + 3) / 4, 256, 0, stream>>>(Qb, KVb, rowPtr, colIdx, l1s, l1b, ehi, elo, N);

    // layer 2
    qkv_k<<<ggrid, 256, 0, stream>>>(ehi, elo, wfragQKV2, Qb, KVb, N);
    agg_k<<<(N + 3) / 4, 256, 0, stream>>>(Qb, KVb, rowPtr, colIdx, l2s, l2b, ehi, elo, N);

    // output projection
    outproj_k<<<ggrid, 256, 0, stream>>>(ehi, elo, wfragO, invb, (float*)d_out, N);
}

// Round 2
// 488.019 us; speedup vs baseline: 1.0306x; 1.0164x over previous
//
#include <hip/hip_runtime.h>
#include <hip/hip_bf16.h>

#define HEADS 8
#define DIM 128

typedef short s8v __attribute__((ext_vector_type(8)));
typedef float f4v __attribute__((ext_vector_type(4)));

__device__ __forceinline__ float bf2f(unsigned int lo16) {
    union { unsigned int i; float f; } v; v.i = lo16 << 16; return v.f;
}
__device__ __forceinline__ unsigned short f2bf(float f) {
    __hip_bfloat16 h = __float2bfloat16(f);
    return *reinterpret_cast<unsigned short*>(&h);
}
__device__ __forceinline__ int imin(int a, int b) { return a < b ? a : b; }

// DPP butterfly add within 8-lane groups (head groups). CTRL must be imm.
// 0xB1 = quad_perm(1,0,3,2) = xor1; 0x4E = quad_perm(2,3,0,1) = xor2;
// 0x141 = row_half_mirror = lane^7 within each 8-lane half-row.
template<int CTRL>
__device__ __forceinline__ float dpp_add_f(float x) {
    int y = __builtin_amdgcn_update_dpp(0, __float_as_int(x), CTRL, 0xF, 0xF, true);
    return x + __int_as_float(y);
}

// Full-wave (64-lane) sum via classic GCN DPP ladder: row_shr 1/2/4/8 builds
// per-16-row inclusive prefix; row_bcast15 + row_bcast31 fold rows; total in
// lane 63, broadcast back via readlane (SGPR).
__device__ __forceinline__ float wave_allsum(float x) {
    x = dpp_add_f<0x111>(x);  // row_shr:1
    x = dpp_add_f<0x112>(x);  // row_shr:2
    x = dpp_add_f<0x114>(x);  // row_shr:4
    x = dpp_add_f<0x118>(x);  // row_shr:8
    x = dpp_add_f<0x142>(x);  // row_bcast:15
    x = dpp_add_f<0x143>(x);  // row_bcast:31
    return __int_as_float(__builtin_amdgcn_readlane(__float_as_int(x), 63));
}

#if __has_builtin(__builtin_amdgcn_exp2f)
#define fast_exp2(x) __builtin_amdgcn_exp2f(x)
#else
#define fast_exp2(x) __expf(0.6931471805599453f * (x))
#endif

// ---------------------------------------------------------------------------
// Fused setup: per-block dtype sniff (int64 vs int32) + edge convert + degree
// count. Every block redundantly sniffs the first 2 KB (validated logic, R2).
// ---------------------------------------------------------------------------
__global__ __launch_bounds__(256) void setup_k(const void* __restrict__ ei, int n2, int E,
                                               int* __restrict__ out, int* __restrict__ deg) {
    __shared__ int cnt;
    const unsigned int* w = (const unsigned int*)ei;
    if (threadIdx.x == 0) cnt = 0;
    __syncthreads();
    if (w[2 * threadIdx.x + 1] == 0u) atomicAdd(&cnt, 1);
    __syncthreads();
    const bool is64 = cnt > 192;
    int i = blockIdx.x * 256 + threadIdx.x;
    if (i < n2) {
        int v = is64 ? (int)((const long long*)ei)[i] : ((const int*)ei)[i];
        out[i] = v;
        if (i < E) atomicAdd(&deg[v], 1);   // rows half
    }
}

// ---------------------------------------------------------------------------
// CSR scan + scatter (validated in R2)
// ---------------------------------------------------------------------------
__global__ void scan1_k(const int* __restrict__ deg, int n,
                        int* __restrict__ incl, int* __restrict__ blkSums) {
    __shared__ int s[256];
    int i = blockIdx.x * 256 + threadIdx.x;
    int v = (i < n) ? deg[i] : 0;
    s[threadIdx.x] = v;
    __syncthreads();
    for (int off = 1; off < 256; off <<= 1) {
        int t = (threadIdx.x >= off) ? s[threadIdx.x - off] : 0;
        __syncthreads();
        s[threadIdx.x] += t;
        __syncthreads();
    }
    if (i < n) incl[i] = s[threadIdx.x];
    if (threadIdx.x == 255) blkSums[blockIdx.x] = s[255];
}

__global__ void scan2_k(int* __restrict__ blkSums, int nb) {
    __shared__ int s[256];
    int v = (threadIdx.x < nb) ? blkSums[threadIdx.x] : 0;
    s[threadIdx.x] = v;
    __syncthreads();
    for (int off = 1; off < 256; off <<= 1) {
        int t = (threadIdx.x >= off) ? s[threadIdx.x - off] : 0;
        __syncthreads();
        s[threadIdx.x] += t;
        __syncthreads();
    }
    if (threadIdx.x < nb) blkSums[threadIdx.x] = s[threadIdx.x] - v;
}

__global__ void scan3_k(const int* __restrict__ incl, const int* __restrict__ deg,
                        const int* __restrict__ blkOff, int n,
                        int* __restrict__ rowPtr, int* __restrict__ cursor) {
    int i = blockIdx.x * 256 + threadIdx.x;
    if (i < n) {
        int inc = incl[i] + blkOff[blockIdx.x];
        rowPtr[i + 1] = inc;
        cursor[i] = inc - deg[i];
    }
    if (i == 0) rowPtr[0] = 0;
}

__global__ void scatter_k(const int* __restrict__ rows, const int* __restrict__ cols, int E,
                          int* __restrict__ cursor, int* __restrict__ colIdx) {
    int e = blockIdx.x * 256 + threadIdx.x;
    if (e < E) {
        int pos = atomicAdd(&cursor[rows[e]], 1);
        colIdx[pos] = cols[e];
    }
}

// ---------------------------------------------------------------------------
// All weight-fragment builds in ONE kernel; job table by blockIdx.
// Frag f = (comp*split + p)*perPhase + (nt*KS + ks)*64 + lane; element j =
// W[ks*32 + (lane>>4)*8 + j][p*(Nd/split) + nt*16 + (lane&15)]. hi/lo bf16.
// ---------------------------------------------------------------------------
__global__ __launch_bounds__(256) void build_all_wfrag_k(
    const float* __restrict__ Wp, const float* __restrict__ q1, const float* __restrict__ k1,
    const float* __restrict__ v1, const float* __restrict__ q2, const float* __restrict__ k2,
    const float* __restrict__ v2, const float* __restrict__ invw,
    unsigned short* __restrict__ wfragP, unsigned short* __restrict__ wfragQKV1,
    unsigned short* __restrict__ wfragQKV2, unsigned short* __restrict__ wfragO)
{
    const int b = blockIdx.x;
    const float* W; unsigned short* dst; int Kd, Nd, ncomp, fb;
    const int split = 2;
    if (b < 32) { W = Wp; dst = wfragP; Kd = 256; Nd = 128; ncomp = 2; fb = b; }
    else if (b < 128) {
        int j = (b - 32) >> 4, r = (b - 32) & 15;
        const float* ws[6] = { q1, k1, v1, q2, k2, v2 };
        W = ws[j];
        dst = ((j < 3) ? wfragQKV1 : wfragQKV2) + (size_t)(j % 3) * 2 * 128 * 128;
        Kd = 128; Nd = 128; ncomp = 2; fb = r;
    } else { W = invw; dst = wfragO; Kd = 128; Nd = 256; ncomp = 1; fb = b - 128; }

    int f = fb * 256 + threadIdx.x;
    int KS = Kd >> 5;
    int perPhase = (Nd / 16 / split) * KS * 64;
    if (f >= ncomp * split * perPhase) return;
    int comp = f / (split * perPhase);
    int r1 = f - comp * split * perPhase;
    int p = r1 / perPhase;
    int r = r1 - p * perPhase;
    int nt = r / (KS * 64);
    int r2 = r - nt * KS * 64;
    int ks = r2 >> 6, lane = r2 & 63;
    int n = p * (Nd / split) + nt * 16 + (lane & 15);
    int k0 = ks * 32 + (lane >> 4) * 8;
    unsigned short tmp[8];
#pragma unroll
    for (int j = 0; j < 8; j++) {
        float w = W[(size_t)(k0 + j) * Nd + n];
        unsigned short hi = f2bf(w);
        tmp[j] = (comp == 0) ? hi : f2bf(w - bf2f(hi));
    }
#pragma unroll
    for (int j = 0; j < 8; j++) dst[(size_t)f * 8 + j] = tmp[j];
}

// ---------------------------------------------------------------------------
// Input projection (LDS-free): trunk planes = x(f32)[M,256] @ W_P + b + pos.
// R-this: BOTH 64-col phases fused into one pass (NTp=8) so x is read ONCE.
// 256 thr = 4 waves, 1 row-pair each. B-frags read wave-coalesced from global
// (L2-resident). Ah*Bh+Ah*Bl+Al*Bh. col = g*16 + m16 (g = p*4 + nt).
// ---------------------------------------------------------------------------
__global__ __launch_bounds__(256) void proj_k(
    const float* __restrict__ A, const unsigned short* __restrict__ wfrag,
    const float* __restrict__ b0, const float* __restrict__ b1,
    unsigned short* __restrict__ ehi, unsigned short* __restrict__ elo, int M)
{
    constexpr int KD = 256, KS = 8, NT = 8;
    constexpr int FRp = 4 * KS * 64;  // 2048 frags per (comp,phase) plane
    const int lane = threadIdx.x & 63;
    const int m16 = lane & 15, q4 = lane >> 4;
    const int pairIdx = blockIdx.x * 4 + (threadIdx.x >> 6);
    const int nPairs = (M + 31) >> 5;
    if (pairIdx >= nPairs) return;

    const int row0 = pairIdx * 32;
    const int rA0 = imin(row0 + m16, M - 1);
    const int rA1 = imin(row0 + 16 + m16, M - 1);

    f4v acc0[NT], acc1[NT];
#pragma unroll
    for (int g = 0; g < NT; g++) { acc0[g] = (f4v){0,0,0,0}; acc1[g] = (f4v){0,0,0,0}; }

    for (int ks = 0; ks < KS; ks++) {
        const f4v* pa0 = (const f4v*)(A + (size_t)rA0 * KD + ks * 32 + q4 * 8);
        const f4v* pa1 = (const f4v*)(A + (size_t)rA1 * KD + ks * 32 + q4 * 8);
        f4v xa = pa0[0], xb = pa0[1], ya = pa1[0], yb = pa1[1];
        s8v a0h, a0l, a1h, a1l;
#pragma unroll
        for (int j = 0; j < 4; j++) {
            unsigned short h;
            h = f2bf(xa[j]); a0h[j] = (short)h; a0l[j] = (short)f2bf(xa[j] - bf2f(h));
            h = f2bf(xb[j]); a0h[4 + j] = (short)h; a0l[4 + j] = (short)f2bf(xb[j] - bf2f(h));
            h = f2bf(ya[j]); a1h[j] = (short)h; a1l[j] = (short)f2bf(ya[j] - bf2f(h));
            h = f2bf(yb[j]); a1h[4 + j] = (short)h; a1l[4 + j] = (short)f2bf(yb[j] - bf2f(h));
        }
#pragma unroll
        for (int g = 0; g < NT; g++) {
            const int p = g >> 2, nt = g & 3;
            const size_t fi = ((size_t)(nt * KS + ks) * 64 + lane) * 8;
            s8v bh = *(const s8v*)(wfrag + ((size_t)(0 * 2 + p) * FRp) * 8 + fi);
            s8v bl = *(const s8v*)(wfrag + ((size_t)(1 * 2 + p) * FRp) * 8 + fi);
            acc0[g] = __builtin_amdgcn_mfma_f32_16x16x32_bf16(a0h, bh, acc0[g], 0, 0, 0);
            acc0[g] = __builtin_amdgcn_mfma_f32_16x16x32_bf16(a0h, bl, acc0[g], 0, 0, 0);
            acc0[g] = __builtin_amdgcn_mfma_f32_16x16x32_bf16(a0l, bh, acc0[g], 0, 0, 0);
            acc1[g] = __builtin_amdgcn_mfma_f32_16x16x32_bf16(a1h, bh, acc1[g], 0, 0, 0);
            acc1[g] = __builtin_amdgcn_mfma_f32_16x16x32_bf16(a1h, bl, acc1[g], 0, 0, 0);
            acc1[g] = __builtin_amdgcn_mfma_f32_16x16x32_bf16(a1l, bh, acc1[g], 0, 0, 0);
        }
    }

#pragma unroll
    for (int g = 0; g < NT; g++) {
        const int col = g * 16 + m16;
        const float bias = b0[col] + b1[col];
#pragma unroll
        for (int r = 0; r < 4; r++) {
            const int gr0 = row0 + q4 * 4 + r;
            if (gr0 < M) {
                float v = acc0[g][r] + bias;
                unsigned short h = f2bf(v);
                ehi[(size_t)gr0 * DIM + col] = h;
                elo[(size_t)gr0 * DIM + col] = f2bf(v - bf2f(h));
            }
            const int gr1 = gr0 + 16;
            if (gr1 < M && row0 + 16 < M) {
                float v = acc1[g][r] + bias;
                unsigned short h = f2bf(v);
                ehi[(size_t)gr1 * DIM + col] = h;
                elo[(size_t)gr1 * DIM + col] = f2bf(v - bf2f(h));
            }
        }
    }
}

// ---------------------------------------------------------------------------
// Fused QKV (LDS-free): A = trunk planes. Q f32 (split-precision), K,V bf16.
// R-this: KV layout interleaved per-dim: KV[row][2d]=K[d], KV[row][2d+1]=V[d]
// -> agg_k reads one 8B word per edge; here one 4B store per (K,V) pair.
// grid (391,2).
// ---------------------------------------------------------------------------
__global__ __launch_bounds__(256) void qkv_k(
    const unsigned short* __restrict__ ehi, const unsigned short* __restrict__ elo,
    const unsigned short* __restrict__ wfrag,
    float* __restrict__ Qb, unsigned short* __restrict__ KVb, int M)
{
    constexpr int KS = 4, NTp = 4;
    constexpr int FRp = NTp * KS * 64;   // 1024
    constexpr int MATFR = 4 * FRp;       // 2 comp x 2 phase
    const int lane = threadIdx.x & 63;
    const int m16 = lane & 15, q4 = lane >> 4;
    const int phase = blockIdx.y;
    const int pairIdx = blockIdx.x * 4 + (threadIdx.x >> 6);
    const int nPairs = (M + 31) >> 5;
    if (pairIdx >= nPairs) return;

    const int row0 = pairIdx * 32;
    const int rA0 = imin(row0 + m16, M - 1);
    const int rA1 = imin(row0 + 16 + m16, M - 1);

    s8v a0h[KS], a0l[KS], a1h[KS], a1l[KS];
#pragma unroll
    for (int ks = 0; ks < KS; ks++) {
        a0h[ks] = *(const s8v*)(ehi + (size_t)rA0 * DIM + ks * 32 + q4 * 8);
        a0l[ks] = *(const s8v*)(elo + (size_t)rA0 * DIM + ks * 32 + q4 * 8);
        a1h[ks] = *(const s8v*)(ehi + (size_t)rA1 * DIM + ks * 32 + q4 * 8);
        a1l[ks] = *(const s8v*)(elo + (size_t)rA1 * DIM + ks * 32 + q4 * 8);
    }

    f4v aQ0[NTp], aQ1[NTp], aK0[NTp], aK1[NTp], aV0[NTp], aV1[NTp];
#pragma unroll
    for (int nt = 0; nt < NTp; nt++) {
        aQ0[nt] = (f4v){0,0,0,0}; aQ1[nt] = (f4v){0,0,0,0};
        aK0[nt] = (f4v){0,0,0,0}; aK1[nt] = (f4v){0,0,0,0};
        aV0[nt] = (f4v){0,0,0,0}; aV1[nt] = (f4v){0,0,0,0};
    }

#pragma unroll
    for (int ks = 0; ks < KS; ks++) {
#pragma unroll
        for (int nt = 0; nt < NTp; nt++) {
            const size_t fi = ((size_t)(nt * KS + ks) * 64 + lane) * 8;
            s8v qh = *(const s8v*)(wfrag + (size_t)(0 * MATFR + (0 * 2 + phase) * FRp) * 8 + fi);
            s8v ql = *(const s8v*)(wfrag + (size_t)(0 * MATFR + (1 * 2 + phase) * FRp) * 8 + fi);
            s8v kh = *(const s8v*)(wfrag + (size_t)(1 * MATFR + (0 * 2 + phase) * FRp) * 8 + fi);
            s8v kl = *(const s8v*)(wfrag + (size_t)(1 * MATFR + (1 * 2 + phase) * FRp) * 8 + fi);
            s8v vh = *(const s8v*)(wfrag + (size_t)(2 * MATFR + (0 * 2 + phase) * FRp) * 8 + fi);
            aQ0[nt] = __builtin_amdgcn_mfma_f32_16x16x32_bf16(a0h[ks], qh, aQ0[nt], 0, 0, 0);
            aQ0[nt] = __builtin_amdgcn_mfma_f32_16x16x32_bf16(a0h[ks], ql, aQ0[nt], 0, 0, 0);
            aQ0[nt] = __builtin_amdgcn_mfma_f32_16x16x32_bf16(a0l[ks], qh, aQ0[nt], 0, 0, 0);
            aQ1[nt] = __builtin_amdgcn_mfma_f32_16x16x32_bf16(a1h[ks], qh, aQ1[nt], 0, 0, 0);
            aQ1[nt] = __builtin_amdgcn_mfma_f32_16x16x32_bf16(a1h[ks], ql, aQ1[nt], 0, 0, 0);
            aQ1[nt] = __builtin_amdgcn_mfma_f32_16x16x32_bf16(a1l[ks], qh, aQ1[nt], 0, 0, 0);
            aK0[nt] = __builtin_amdgcn_mfma_f32_16x16x32_bf16(a0h[ks], kh, aK0[nt], 0, 0, 0);
            aK0[nt] = __builtin_amdgcn_mfma_f32_16x16x32_bf16(a0h[ks], kl, aK0[nt], 0, 0, 0);
            aK0[nt] = __builtin_amdgcn_mfma_f32_16x16x32_bf16(a0l[ks], kh, aK0[nt], 0, 0, 0);
            aK1[nt] = __builtin_amdgcn_mfma_f32_16x16x32_bf16(a1h[ks], kh, aK1[nt], 0, 0, 0);
            aK1[nt] = __builtin_amdgcn_mfma_f32_16x16x32_bf16(a1h[ks], kl, aK1[nt], 0, 0, 0);
            aK1[nt] = __builtin_amdgcn_mfma_f32_16x16x32_bf16(a1l[ks], kh, aK1[nt], 0, 0, 0);
            aV0[nt] = __builtin_amdgcn_mfma_f32_16x16x32_bf16(a0h[ks], vh, aV0[nt], 0, 0, 0);
            aV0[nt] = __builtin_amdgcn_mfma_f32_16x16x32_bf16(a0l[ks], vh, aV0[nt], 0, 0, 0);
            aV1[nt] = __builtin_amdgcn_mfma_f32_16x16x32_bf16(a1h[ks], vh, aV1[nt], 0, 0, 0);
            aV1[nt] = __builtin_amdgcn_mfma_f32_16x16x32_bf16(a1l[ks], vh, aV1[nt], 0, 0, 0);
        }
    }

#pragma unroll
    for (int nt = 0; nt < NTp; nt++) {
        const int col = phase * 64 + nt * 16 + m16;
#pragma unroll
        for (int r = 0; r < 4; r++) {
            const int gr0 = row0 + q4 * 4 + r;
            if (gr0 < M) {
                Qb[(size_t)gr0 * DIM + col] = aQ0[nt][r];
                *(unsigned int*)(KVb + (size_t)gr0 * 256 + 2 * col) =
                    (unsigned int)f2bf(aK0[nt][r]) | ((unsigned int)f2bf(aV0[nt][r]) << 16);
            }
            const int gr1 = gr0 + 16;
            if (gr1 < M && row0 + 16 < M) {
                Qb[(size_t)gr1 * DIM + col] = aQ1[nt][r];
                *(unsigned int*)(KVb + (size_t)gr1 * 256 + 2 * col) =
                    (unsigned int)f2bf(aK1[nt][r]) | ((unsigned int)f2bf(aV1[nt][r]) << 16);
            }
        }
    }
}

// ---------------------------------------------------------------------------
// Output projection (LDS-free): d_out(f32)[M,256] = trunk @ inv_w + inv_b.
// ---------------------------------------------------------------------------
__global__ __launch_bounds__(256) void outproj_k(
    const unsigned short* __restrict__ ehi, const unsigned short* __restrict__ elo,
    const unsigned short* __restrict__ wfrag, const float* __restrict__ b0,
    float* __restrict__ Out, int M)
{
    constexpr int KS = 4, NTp = 8, NOUT = 256;
    constexpr int FRp = NTp * KS * 64;  // 2048
    const int lane = threadIdx.x & 63;
    const int m16 = lane & 15, q4 = lane >> 4;
    const int phase = blockIdx.y;
    const int pairIdx = blockIdx.x * 4 + (threadIdx.x >> 6);
    const int nPairs = (M + 31) >> 5;
    if (pairIdx >= nPairs) return;

    const int row0 = pairIdx * 32;
    const int rA0 = imin(row0 + m16, M - 1);
    const int rA1 = imin(row0 + 16 + m16, M - 1);

    s8v a0h[KS], a0l[KS], a1h[KS], a1l[KS];
#pragma unroll
    for (int ks = 0; ks < KS; ks++) {
        a0h[ks] = *(const s8v*)(ehi + (size_t)rA0 * DIM + ks * 32 + q4 * 8);
        a0l[ks] = *(const s8v*)(elo + (size_t)rA0 * DIM + ks * 32 + q4 * 8);
        a1h[ks] = *(const s8v*)(ehi + (size_t)rA1 * DIM + ks * 32 + q4 * 8);
        a1l[ks] = *(const s8v*)(elo + (size_t)rA1 * DIM + ks * 32 + q4 * 8);
    }

    f4v acc0[NTp], acc1[NTp];
#pragma unroll
    for (int nt = 0; nt < NTp; nt++) { acc0[nt] = (f4v){0,0,0,0}; acc1[nt] = (f4v){0,0,0,0}; }

#pragma unroll
    for (int ks = 0; ks < KS; ks++) {
#pragma unroll
        for (int nt = 0; nt < NTp; nt++) {
            s8v b = *(const s8v*)(wfrag + ((size_t)phase * FRp + (size_t)(nt * KS + ks) * 64 + lane) * 8);
            acc0[nt] = __builtin_amdgcn_mfma_f32_16x16x32_bf16(a0h[ks], b, acc0[nt], 0, 0, 0);
            acc0[nt] = __builtin_amdgcn_mfma_f32_16x16x32_bf16(a0l[ks], b, acc0[nt], 0, 0, 0);
            acc1[nt] = __builtin_amdgcn_mfma_f32_16x16x32_bf16(a1h[ks], b, acc1[nt], 0, 0, 0);
            acc1[nt] = __builtin_amdgcn_mfma_f32_16x16x32_bf16(a1l[ks], b, acc1[nt], 0, 0, 0);
        }
    }

#pragma unroll
    for (int nt = 0; nt < NTp; nt++) {
        const int col = phase * 128 + nt * 16 + m16;
        const float bias = b0[col];
#pragma unroll
        for (int r = 0; r < 4; r++) {
            const int gr0 = row0 + q4 * 4 + r;
            if (gr0 < M) Out[(size_t)gr0 * NOUT + col] = acc0[nt][r] + bias;
            const int gr1 = gr0 + 16;
            if (gr1 < M && row0 + 16 < M) Out[(size_t)gr1 * NOUT + col] = acc1[nt][r] + bias;
        }
    }
}

// ---------------------------------------------------------------------------
// Fused attention + residual + LayerNorm. One wave per node; lane owns dims
// (2*lane, 2*lane+1); head = lane>>3. 4-edge chunks, double-buffered prefetch.
// R-this: interleaved KV -> ONE 8B load per edge per lane; branchless inner
// body (clamped idx + cndmask on w) so the unroll is straight-line; LN reduce
// via DPP row_shr/bcast ladder instead of 12 ds_bpermute.
// ---------------------------------------------------------------------------
__global__ __launch_bounds__(256) void agg_k(
    const float* __restrict__ Q, const unsigned short* __restrict__ KV,
    const int* __restrict__ rowPtr, const int* __restrict__ colIdx,
    const float* __restrict__ ln_s, const float* __restrict__ ln_b,
    unsigned short* __restrict__ ehi, unsigned short* __restrict__ elo, int n)
{
    const int node = blockIdx.x * 4 + (threadIdx.x >> 6);
    if (node >= n) return;
    const int lane = threadIdx.x & 63;
    const int d = lane * 2;

    constexpr float LOG2E = 1.4426950408889634f;
    constexpr float CLAMP = 10.0f * LOG2E;   // clip(t,±10) in 2^x domain

    const float2 qraw = *(const float2*)(Q + (size_t)node * DIM + d);
    const float qx = qraw.x * LOG2E, qy = qraw.y * LOG2E;
    const unsigned int rh = *(const unsigned int*)(ehi + (size_t)node * DIM + d);
    const unsigned int rl = *(const unsigned int*)(elo + (size_t)node * DIM + d);
    const float r0 = bf2f(rh & 0xffffu) + bf2f(rl & 0xffffu);
    const float r1 = bf2f(rh >> 16) + bf2f(rl >> 16);

    const int e0 = rowPtr[node], e1 = rowPtr[node + 1];
    float acc0 = 0.f, acc1 = 0.f, den = 0.f;

    if (e1 > e0) {
        const uint2* KV2 = (const uint2*)KV;   // row = 64 uint2; lane l -> {K2l,V2l,K2l+1,V2l+1}
        const int emax = e1 - 1;
        uint2 cA[4], cB[4];
#define LOADC(arr, base_)                                               \
        {                                                               \
            _Pragma("unroll")                                           \
            for (int j = 0; j < 4; j++) {                               \
                int cc = colIdx[imin((base_) + j, emax)];               \
                arr[j] = KV2[(cc << 6) + lane];                         \
            }                                                           \
        }
#define COMP(arr, base_)                                                \
        {                                                               \
            _Pragma("unroll")                                           \
            for (int j = 0; j < 4; j++) {                               \
                const unsigned int w0 = arr[j].x, w1 = arr[j].y;        \
                float p = qx * bf2f(w0 & 0xffffu)                       \
                        + qy * bf2f(w1 & 0xffffu);                      \
                p = dpp_add_f<0xB1>(p);   /* xor1 */                    \
                p = dpp_add_f<0x4E>(p);   /* xor2 */                    \
                p = dpp_add_f<0x141>(p);  /* ^7: other quad sum */      \
                p = fminf(fmaxf(p, -CLAMP), CLAMP);                     \
                float w = fast_exp2(p);                                 \
                w = ((base_) + j < e1) ? w : 0.f;                       \
                den += w;                                               \
                acc0 += w * bf2f(w0 >> 16);                             \
                acc1 += w * bf2f(w1 >> 16);                             \
            }                                                           \
        }
        int base = e0;
        LOADC(cA, base)
        while (true) {
            int nxt = base + 4;
            if (nxt < e1) LOADC(cB, nxt)
            COMP(cA, base)
            base = nxt;
            if (base >= e1) break;
            int nxt2 = base + 4;
            if (nxt2 < e1) LOADC(cA, nxt2)
            COMP(cB, base)
            base = nxt2;
            if (base >= e1) break;
        }
#undef LOADC
#undef COMP
    }
    const float inv = 1.f / (den + 1e-8f);
    const float o0 = acc0 * inv + r0;
    const float o1 = acc1 * inv + r1;

    const float s  = wave_allsum(o0 + o1);
    const float s2 = wave_allsum(o0 * o0 + o1 * o1);
    const float mu = s * (1.f / 128.f);
    const float var = s2 * (1.f / 128.f) - mu * mu;
    const float rs = rsqrtf(var + 1e-6f);
    const float y0 = (o0 - mu) * rs * ln_s[d] + ln_b[d];
    const float y1 = (o1 - mu) * rs * ln_s[d + 1] + ln_b[d + 1];
    const unsigned short h0 = f2bf(y0), h1 = f2bf(y1);
    const unsigned short l0 = f2bf(y0 - bf2f(h0)), l1 = f2bf(y1 - bf2f(h1));
    *(unsigned int*)(ehi + (size_t)node * DIM + d) = (unsigned int)h0 | ((unsigned int)h1 << 16);
    *(unsigned int*)(elo + (size_t)node * DIM + d) = (unsigned int)l0 | ((unsigned int)l1 << 16);
}

// ---------------------------------------------------------------------------
// Launch
// ---------------------------------------------------------------------------
extern "C" void kernel_launch(void* const* d_in, const int* in_sizes, int n_in,
                              void* d_out, int out_size, void* d_ws, size_t ws_size,
                              hipStream_t stream)
{
    const float* x    = (const float*)d_in[0];
    const void*  ei   = d_in[1];
    const float* Wp   = (const float*)d_in[2];
    const float* Wpb  = (const float*)d_in[3];
    const float* Wpos = (const float*)d_in[4];
    const float* q1   = (const float*)d_in[5];
    const float* k1   = (const float*)d_in[6];
    const float* v1   = (const float*)d_in[7];
    const float* l1s  = (const float*)d_in[8];
    const float* l1b  = (const float*)d_in[9];
    const float* q2   = (const float*)d_in[10];
    const float* k2   = (const float*)d_in[11];
    const float* v2   = (const float*)d_in[12];
    const float* l2s  = (const float*)d_in[13];
    const float* l2b  = (const float*)d_in[14];
    const float* invw = (const float*)d_in[15];
    const float* invb = (const float*)d_in[16];

    const int N = in_sizes[0] / 256;   // 50000
    const int E = in_sizes[1] / 2;     // 800000

    char* p = (char*)d_ws;
    auto carve = [&](size_t bytes) -> void* {
        void* r = (void*)p;
        p += (bytes + 255) & ~(size_t)255;
        return r;
    };
    unsigned short* ehi = (unsigned short*)carve((size_t)N * DIM * 2);
    unsigned short* elo = (unsigned short*)carve((size_t)N * DIM * 2);
    float*          Qb  = (float*)carve((size_t)N * DIM * 4);
    unsigned short* KVb = (unsigned short*)carve((size_t)N * 256 * 2);
    int*   deg    = (int*)carve((size_t)N * 4);
    int*   incl   = (int*)carve((size_t)N * 4);
    int*   blkS   = (int*)carve(1024);
    int*   rowPtr = (int*)carve((size_t)(N + 1) * 4);
    int*   cursor = (int*)carve((size_t)N * 4);
    int*   colIdx = (int*)carve((size_t)E * 4);
    int*   rc     = (int*)carve((size_t)2 * E * 4);
    unsigned short* wfragP    = (unsigned short*)carve((size_t)2 * 256 * 128 * 2);
    unsigned short* wfragQKV1 = (unsigned short*)carve((size_t)3 * 2 * 128 * 128 * 2);
    unsigned short* wfragQKV2 = (unsigned short*)carve((size_t)3 * 2 * 128 * 128 * 2);
    unsigned short* wfragO    = (unsigned short*)carve((size_t)128 * 256 * 2);

    int* rows = rc;
    int* cols = rc + E;

    const int nb  = (N + 255) / 256;
    const int ebl = (E + 255) / 256;
    const int nPairs = (N + 31) / 32;
    const dim3 ggrid((nPairs + 3) / 4, 2);
    const dim3 ggridP((nPairs + 3) / 4, 1);

    // CSR build (fused setup: dtype sniff + convert + degree count)
    hipMemsetAsync(deg, 0, (size_t)N * 4, stream);
    setup_k<<<(2 * E + 255) / 256, 256, 0, stream>>>(ei, 2 * E, E, rc, deg);
    scan1_k<<<nb, 256, 0, stream>>>(deg, N, incl, blkS);
    scan2_k<<<1, 256, 0, stream>>>(blkS, nb);
    scan3_k<<<nb, 256, 0, stream>>>(incl, deg, blkS, N, rowPtr, cursor);
    scatter_k<<<ebl, 256, 0, stream>>>(rows, cols, E, cursor, colIdx);

    // all weight fragments in one launch
    build_all_wfrag_k<<<144, 256, 0, stream>>>(Wp, q1, k1, v1, q2, k2, v2, invw,
                                               wfragP, wfragQKV1, wfragQKV2, wfragO);

    // input projection -> trunk planes (both phases fused; x read once)
    proj_k<<<ggridP, 256, 0, stream>>>(x, wfragP, Wpb, Wpos, ehi, elo, N);

    // layer 1
    qkv_k<<<ggrid, 256, 0, stream>>>(ehi, elo, wfragQKV1, Qb, KVb, N);
    agg_k<<<(N + 3) / 4, 256, 0, stream>>>(Qb, KVb, rowPtr, colIdx, l1s, l1b, ehi, elo, N);

    // layer 2
    qkv_k<<<ggrid, 256, 0, stream>>>(ehi, elo, wfragQKV2, Qb, KVb, N);
    agg_k<<<(N + 3) / 4, 256, 0, stream>>>(Qb, KVb, rowPtr, colIdx, l2s, l2b, ehi, elo, N);

    // output projection
    outproj_k<<<ggrid, 256, 0, stream>>>(ehi, elo, wfragO, invb, (float*)d_out, N);
}

// Round 3
// 486.257 us; speedup vs baseline: 1.0343x; 1.0036x over previous
//
#include <hip/hip_runtime.h>
#include <hip/hip_bf16.h>

#define HEADS 8
#define DIM 128

typedef short s8v __attribute__((ext_vector_type(8)));
typedef float f4v __attribute__((ext_vector_type(4)));

__device__ __forceinline__ float bf2f(unsigned int lo16) {
    union { unsigned int i; float f; } v; v.i = lo16 << 16; return v.f;
}
__device__ __forceinline__ float bf2f_hi(unsigned int w) {
    union { unsigned int i; float f; } v; v.i = w & 0xffff0000u; return v.f;
}
__device__ __forceinline__ unsigned short f2bf(float f) {
    __hip_bfloat16 h = __float2bfloat16(f);
    return *reinterpret_cast<unsigned short*>(&h);
}
__device__ __forceinline__ int imin(int a, int b) { return a < b ? a : b; }

// DPP butterfly add within 8-lane groups (head groups). CTRL must be imm.
// 0xB1 = quad_perm(1,0,3,2) = xor1; 0x4E = quad_perm(2,3,0,1) = xor2;
// 0x141 = row_half_mirror = lane^7 within each 8-lane half-row.
template<int CTRL>
__device__ __forceinline__ float dpp_add_f(float x) {
    int y = __builtin_amdgcn_update_dpp(0, __float_as_int(x), CTRL, 0xF, 0xF, true);
    return x + __int_as_float(y);
}

// Full-wave (64-lane) sum via classic GCN DPP ladder: row_shr 1/2/4/8 builds
// per-16-row inclusive prefix; row_bcast15 + row_bcast31 fold rows; total in
// lane 63, broadcast back via readlane (SGPR).
__device__ __forceinline__ float wave_allsum(float x) {
    x = dpp_add_f<0x111>(x);  // row_shr:1
    x = dpp_add_f<0x112>(x);  // row_shr:2
    x = dpp_add_f<0x114>(x);  // row_shr:4
    x = dpp_add_f<0x118>(x);  // row_shr:8
    x = dpp_add_f<0x142>(x);  // row_bcast:15
    x = dpp_add_f<0x143>(x);  // row_bcast:31
    return __int_as_float(__builtin_amdgcn_readlane(__float_as_int(x), 63));
}

#if __has_builtin(__builtin_amdgcn_exp2f)
#define fast_exp2(x) __builtin_amdgcn_exp2f(x)
#else
#define fast_exp2(x) __expf(0.6931471805599453f * (x))
#endif

// ---------------------------------------------------------------------------
// Fused setup: per-block dtype sniff (int64 vs int32) + edge convert + degree
// count. Every block redundantly sniffs the first 2 KB (validated logic, R2).
// ---------------------------------------------------------------------------
__global__ __launch_bounds__(256) void setup_k(const void* __restrict__ ei, int n2, int E,
                                               int* __restrict__ out, int* __restrict__ deg) {
    __shared__ int cnt;
    const unsigned int* w = (const unsigned int*)ei;
    if (threadIdx.x == 0) cnt = 0;
    __syncthreads();
    if (w[2 * threadIdx.x + 1] == 0u) atomicAdd(&cnt, 1);
    __syncthreads();
    const bool is64 = cnt > 192;
    int i = blockIdx.x * 256 + threadIdx.x;
    if (i < n2) {
        int v = is64 ? (int)((const long long*)ei)[i] : ((const int*)ei)[i];
        out[i] = v;
        if (i < E) atomicAdd(&deg[v], 1);   // rows half
    }
}

// ---------------------------------------------------------------------------
// CSR scan + scatter (validated in R2)
// ---------------------------------------------------------------------------
__global__ void scan1_k(const int* __restrict__ deg, int n,
                        int* __restrict__ incl, int* __restrict__ blkSums) {
    __shared__ int s[256];
    int i = blockIdx.x * 256 + threadIdx.x;
    int v = (i < n) ? deg[i] : 0;
    s[threadIdx.x] = v;
    __syncthreads();
    for (int off = 1; off < 256; off <<= 1) {
        int t = (threadIdx.x >= off) ? s[threadIdx.x - off] : 0;
        __syncthreads();
        s[threadIdx.x] += t;
        __syncthreads();
    }
    if (i < n) incl[i] = s[threadIdx.x];
    if (threadIdx.x == 255) blkSums[blockIdx.x] = s[255];
}

__global__ void scan2_k(int* __restrict__ blkSums, int nb) {
    __shared__ int s[256];
    int v = (threadIdx.x < nb) ? blkSums[threadIdx.x] : 0;
    s[threadIdx.x] = v;
    __syncthreads();
    for (int off = 1; off < 256; off <<= 1) {
        int t = (threadIdx.x >= off) ? s[threadIdx.x - off] : 0;
        __syncthreads();
        s[threadIdx.x] += t;
        __syncthreads();
    }
    if (threadIdx.x < nb) blkSums[threadIdx.x] = s[threadIdx.x] - v;
}

__global__ void scan3_k(const int* __restrict__ incl, const int* __restrict__ deg,
                        const int* __restrict__ blkOff, int n,
                        int* __restrict__ rowPtr, int* __restrict__ cursor) {
    int i = blockIdx.x * 256 + threadIdx.x;
    if (i < n) {
        int inc = incl[i] + blkOff[blockIdx.x];
        rowPtr[i + 1] = inc;
        cursor[i] = inc - deg[i];
    }
    if (i == 0) rowPtr[0] = 0;
}

__global__ void scatter_k(const int* __restrict__ rows, const int* __restrict__ cols, int E,
                          int* __restrict__ cursor, int* __restrict__ colIdx) {
    int e = blockIdx.x * 256 + threadIdx.x;
    if (e < E) {
        int pos = atomicAdd(&cursor[rows[e]], 1);
        colIdx[pos] = cols[e];
    }
}

// ---------------------------------------------------------------------------
// All weight-fragment builds in ONE kernel; job table by blockIdx.
// Frag f = (comp*split + p)*perPhase + (nt*KS + ks)*64 + lane; element j =
// W[ks*32 + (lane>>4)*8 + j][p*(Nd/split) + nt*16 + (lane&15)]. hi/lo bf16.
// ---------------------------------------------------------------------------
__global__ __launch_bounds__(256) void build_all_wfrag_k(
    const float* __restrict__ Wp, const float* __restrict__ q1, const float* __restrict__ k1,
    const float* __restrict__ v1, const float* __restrict__ q2, const float* __restrict__ k2,
    const float* __restrict__ v2, const float* __restrict__ invw,
    unsigned short* __restrict__ wfragP, unsigned short* __restrict__ wfragQKV1,
    unsigned short* __restrict__ wfragQKV2, unsigned short* __restrict__ wfragO)
{
    const int b = blockIdx.x;
    const float* W; unsigned short* dst; int Kd, Nd, ncomp, fb;
    const int split = 2;
    if (b < 32) { W = Wp; dst = wfragP; Kd = 256; Nd = 128; ncomp = 2; fb = b; }
    else if (b < 128) {
        int j = (b - 32) >> 4, r = (b - 32) & 15;
        const float* ws[6] = { q1, k1, v1, q2, k2, v2 };
        W = ws[j];
        dst = ((j < 3) ? wfragQKV1 : wfragQKV2) + (size_t)(j % 3) * 2 * 128 * 128;
        Kd = 128; Nd = 128; ncomp = 2; fb = r;
    } else { W = invw; dst = wfragO; Kd = 128; Nd = 256; ncomp = 1; fb = b - 128; }

    int f = fb * 256 + threadIdx.x;
    int KS = Kd >> 5;
    int perPhase = (Nd / 16 / split) * KS * 64;
    if (f >= ncomp * split * perPhase) return;
    int comp = f / (split * perPhase);
    int r1 = f - comp * split * perPhase;
    int p = r1 / perPhase;
    int r = r1 - p * perPhase;
    int nt = r / (KS * 64);
    int r2 = r - nt * KS * 64;
    int ks = r2 >> 6, lane = r2 & 63;
    int n = p * (Nd / split) + nt * 16 + (lane & 15);
    int k0 = ks * 32 + (lane >> 4) * 8;
    unsigned short tmp[8];
#pragma unroll
    for (int j = 0; j < 8; j++) {
        float w = W[(size_t)(k0 + j) * Nd + n];
        unsigned short hi = f2bf(w);
        tmp[j] = (comp == 0) ? hi : f2bf(w - bf2f(hi));
    }
#pragma unroll
    for (int j = 0; j < 8; j++) dst[(size_t)f * 8 + j] = tmp[j];
}

// ---------------------------------------------------------------------------
// Input projection (LDS-free): trunk planes = x(f32)[M,256] @ W_P + b + pos.
// Both 64-col phases fused into one pass (NT=8) so x is read ONCE.
// 256 thr = 4 waves, 1 row-pair each. B-frags read wave-coalesced from global
// (L2-resident). Ah*Bh+Ah*Bl+Al*Bh. col = g*16 + m16 (g = p*4 + nt).
// ---------------------------------------------------------------------------
__global__ __launch_bounds__(256) void proj_k(
    const float* __restrict__ A, const unsigned short* __restrict__ wfrag,
    const float* __restrict__ b0, const float* __restrict__ b1,
    unsigned short* __restrict__ ehi, unsigned short* __restrict__ elo, int M)
{
    constexpr int KD = 256, KS = 8, NT = 8;
    constexpr int FRp = 4 * KS * 64;  // 2048 frags per (comp,phase) plane
    const int lane = threadIdx.x & 63;
    const int m16 = lane & 15, q4 = lane >> 4;
    const int pairIdx = blockIdx.x * 4 + (threadIdx.x >> 6);
    const int nPairs = (M + 31) >> 5;
    if (pairIdx >= nPairs) return;

    const int row0 = pairIdx * 32;
    const int rA0 = imin(row0 + m16, M - 1);
    const int rA1 = imin(row0 + 16 + m16, M - 1);

    f4v acc0[NT], acc1[NT];
#pragma unroll
    for (int g = 0; g < NT; g++) { acc0[g] = (f4v){0,0,0,0}; acc1[g] = (f4v){0,0,0,0}; }

    for (int ks = 0; ks < KS; ks++) {
        const f4v* pa0 = (const f4v*)(A + (size_t)rA0 * KD + ks * 32 + q4 * 8);
        const f4v* pa1 = (const f4v*)(A + (size_t)rA1 * KD + ks * 32 + q4 * 8);
        f4v xa = pa0[0], xb = pa0[1], ya = pa1[0], yb = pa1[1];
        s8v a0h, a0l, a1h, a1l;
#pragma unroll
        for (int j = 0; j < 4; j++) {
            unsigned short h;
            h = f2bf(xa[j]); a0h[j] = (short)h; a0l[j] = (short)f2bf(xa[j] - bf2f(h));
            h = f2bf(xb[j]); a0h[4 + j] = (short)h; a0l[4 + j] = (short)f2bf(xb[j] - bf2f(h));
            h = f2bf(ya[j]); a1h[j] = (short)h; a1l[j] = (short)f2bf(ya[j] - bf2f(h));
            h = f2bf(yb[j]); a1h[4 + j] = (short)h; a1l[4 + j] = (short)f2bf(yb[j] - bf2f(h));
        }
#pragma unroll
        for (int g = 0; g < NT; g++) {
            const int p = g >> 2, nt = g & 3;
            const size_t fi = ((size_t)(nt * KS + ks) * 64 + lane) * 8;
            s8v bh = *(const s8v*)(wfrag + ((size_t)(0 * 2 + p) * FRp) * 8 + fi);
            s8v bl = *(const s8v*)(wfrag + ((size_t)(1 * 2 + p) * FRp) * 8 + fi);
            acc0[g] = __builtin_amdgcn_mfma_f32_16x16x32_bf16(a0h, bh, acc0[g], 0, 0, 0);
            acc0[g] = __builtin_amdgcn_mfma_f32_16x16x32_bf16(a0h, bl, acc0[g], 0, 0, 0);
            acc0[g] = __builtin_amdgcn_mfma_f32_16x16x32_bf16(a0l, bh, acc0[g], 0, 0, 0);
            acc1[g] = __builtin_amdgcn_mfma_f32_16x16x32_bf16(a1h, bh, acc1[g], 0, 0, 0);
            acc1[g] = __builtin_amdgcn_mfma_f32_16x16x32_bf16(a1h, bl, acc1[g], 0, 0, 0);
            acc1[g] = __builtin_amdgcn_mfma_f32_16x16x32_bf16(a1l, bh, acc1[g], 0, 0, 0);
        }
    }

#pragma unroll
    for (int g = 0; g < NT; g++) {
        const int col = g * 16 + m16;
        const float bias = b0[col] + b1[col];
#pragma unroll
        for (int r = 0; r < 4; r++) {
            const int gr0 = row0 + q4 * 4 + r;
            if (gr0 < M) {
                float v = acc0[g][r] + bias;
                unsigned short h = f2bf(v);
                ehi[(size_t)gr0 * DIM + col] = h;
                elo[(size_t)gr0 * DIM + col] = f2bf(v - bf2f(h));
            }
            const int gr1 = gr0 + 16;
            if (gr1 < M && row0 + 16 < M) {
                float v = acc1[g][r] + bias;
                unsigned short h = f2bf(v);
                ehi[(size_t)gr1 * DIM + col] = h;
                elo[(size_t)gr1 * DIM + col] = f2bf(v - bf2f(h));
            }
        }
    }
}

// ---------------------------------------------------------------------------
// Fused QKV (LDS-free): A = trunk planes. Q f32 (split-precision), K,V bf16.
// KV layout interleaved per-dim: KV[row][2d]=K[d], KV[row][2d+1]=V[d]
// -> agg_k reads one 8B word per edge; here one 4B store per (K,V) pair.
// grid (391,2).
// ---------------------------------------------------------------------------
__global__ __launch_bounds__(256) void qkv_k(
    const unsigned short* __restrict__ ehi, const unsigned short* __restrict__ elo,
    const unsigned short* __restrict__ wfrag,
    float* __restrict__ Qb, unsigned short* __restrict__ KVb, int M)
{
    constexpr int KS = 4, NTp = 4;
    constexpr int FRp = NTp * KS * 64;   // 1024
    constexpr int MATFR = 4 * FRp;       // 2 comp x 2 phase
    const int lane = threadIdx.x & 63;
    const int m16 = lane & 15, q4 = lane >> 4;
    const int phase = blockIdx.y;
    const int pairIdx = blockIdx.x * 4 + (threadIdx.x >> 6);
    const int nPairs = (M + 31) >> 5;
    if (pairIdx >= nPairs) return;

    const int row0 = pairIdx * 32;
    const int rA0 = imin(row0 + m16, M - 1);
    const int rA1 = imin(row0 + 16 + m16, M - 1);

    s8v a0h[KS], a0l[KS], a1h[KS], a1l[KS];
#pragma unroll
    for (int ks = 0; ks < KS; ks++) {
        a0h[ks] = *(const s8v*)(ehi + (size_t)rA0 * DIM + ks * 32 + q4 * 8);
        a0l[ks] = *(const s8v*)(elo + (size_t)rA0 * DIM + ks * 32 + q4 * 8);
        a1h[ks] = *(const s8v*)(ehi + (size_t)rA1 * DIM + ks * 32 + q4 * 8);
        a1l[ks] = *(const s8v*)(elo + (size_t)rA1 * DIM + ks * 32 + q4 * 8);
    }

    f4v aQ0[NTp], aQ1[NTp], aK0[NTp], aK1[NTp], aV0[NTp], aV1[NTp];
#pragma unroll
    for (int nt = 0; nt < NTp; nt++) {
        aQ0[nt] = (f4v){0,0,0,0}; aQ1[nt] = (f4v){0,0,0,0};
        aK0[nt] = (f4v){0,0,0,0}; aK1[nt] = (f4v){0,0,0,0};
        aV0[nt] = (f4v){0,0,0,0}; aV1[nt] = (f4v){0,0,0,0};
    }

#pragma unroll
    for (int ks = 0; ks < KS; ks++) {
#pragma unroll
        for (int nt = 0; nt < NTp; nt++) {
            const size_t fi = ((size_t)(nt * KS + ks) * 64 + lane) * 8;
            s8v qh = *(const s8v*)(wfrag + (size_t)(0 * MATFR + (0 * 2 + phase) * FRp) * 8 + fi);
            s8v ql = *(const s8v*)(wfrag + (size_t)(0 * MATFR + (1 * 2 + phase) * FRp) * 8 + fi);
            s8v kh = *(const s8v*)(wfrag + (size_t)(1 * MATFR + (0 * 2 + phase) * FRp) * 8 + fi);
            s8v kl = *(const s8v*)(wfrag + (size_t)(1 * MATFR + (1 * 2 + phase) * FRp) * 8 + fi);
            s8v vh = *(const s8v*)(wfrag + (size_t)(2 * MATFR + (0 * 2 + phase) * FRp) * 8 + fi);
            aQ0[nt] = __builtin_amdgcn_mfma_f32_16x16x32_bf16(a0h[ks], qh, aQ0[nt], 0, 0, 0);
            aQ0[nt] = __builtin_amdgcn_mfma_f32_16x16x32_bf16(a0h[ks], ql, aQ0[nt], 0, 0, 0);
            aQ0[nt] = __builtin_amdgcn_mfma_f32_16x16x32_bf16(a0l[ks], qh, aQ0[nt], 0, 0, 0);
            aQ1[nt] = __builtin_amdgcn_mfma_f32_16x16x32_bf16(a1h[ks], qh, aQ1[nt], 0, 0, 0);
            aQ1[nt] = __builtin_amdgcn_mfma_f32_16x16x32_bf16(a1h[ks], ql, aQ1[nt], 0, 0, 0);
            aQ1[nt] = __builtin_amdgcn_mfma_f32_16x16x32_bf16(a1l[ks], qh, aQ1[nt], 0, 0, 0);
            aK0[nt] = __builtin_amdgcn_mfma_f32_16x16x32_bf16(a0h[ks], kh, aK0[nt], 0, 0, 0);
            aK0[nt] = __builtin_amdgcn_mfma_f32_16x16x32_bf16(a0h[ks], kl, aK0[nt], 0, 0, 0);
            aK0[nt] = __builtin_amdgcn_mfma_f32_16x16x32_bf16(a0l[ks], kh, aK0[nt], 0, 0, 0);
            aK1[nt] = __builtin_amdgcn_mfma_f32_16x16x32_bf16(a1h[ks], kh, aK1[nt], 0, 0, 0);
            aK1[nt] = __builtin_amdgcn_mfma_f32_16x16x32_bf16(a1h[ks], kl, aK1[nt], 0, 0, 0);
            aK1[nt] = __builtin_amdgcn_mfma_f32_16x16x32_bf16(a1l[ks], kh, aK1[nt], 0, 0, 0);
            aV0[nt] = __builtin_amdgcn_mfma_f32_16x16x32_bf16(a0h[ks], vh, aV0[nt], 0, 0, 0);
            aV0[nt] = __builtin_amdgcn_mfma_f32_16x16x32_bf16(a0l[ks], vh, aV0[nt], 0, 0, 0);
            aV1[nt] = __builtin_amdgcn_mfma_f32_16x16x32_bf16(a1h[ks], vh, aV1[nt], 0, 0, 0);
            aV1[nt] = __builtin_amdgcn_mfma_f32_16x16x32_bf16(a1l[ks], vh, aV1[nt], 0, 0, 0);
        }
    }

#pragma unroll
    for (int nt = 0; nt < NTp; nt++) {
        const int col = phase * 64 + nt * 16 + m16;
#pragma unroll
        for (int r = 0; r < 4; r++) {
            const int gr0 = row0 + q4 * 4 + r;
            if (gr0 < M) {
                Qb[(size_t)gr0 * DIM + col] = aQ0[nt][r];
                *(unsigned int*)(KVb + (size_t)gr0 * 256 + 2 * col) =
                    (unsigned int)f2bf(aK0[nt][r]) | ((unsigned int)f2bf(aV0[nt][r]) << 16);
            }
            const int gr1 = gr0 + 16;
            if (gr1 < M && row0 + 16 < M) {
                Qb[(size_t)gr1 * DIM + col] = aQ1[nt][r];
                *(unsigned int*)(KVb + (size_t)gr1 * 256 + 2 * col) =
                    (unsigned int)f2bf(aK1[nt][r]) | ((unsigned int)f2bf(aV1[nt][r]) << 16);
            }
        }
    }
}

// ---------------------------------------------------------------------------
// Output projection (LDS-free): d_out(f32)[M,256] = trunk @ inv_w + inv_b.
// ---------------------------------------------------------------------------
__global__ __launch_bounds__(256) void outproj_k(
    const unsigned short* __restrict__ ehi, const unsigned short* __restrict__ elo,
    const unsigned short* __restrict__ wfrag, const float* __restrict__ b0,
    float* __restrict__ Out, int M)
{
    constexpr int KS = 4, NTp = 8, NOUT = 256;
    constexpr int FRp = NTp * KS * 64;  // 2048
    const int lane = threadIdx.x & 63;
    const int m16 = lane & 15, q4 = lane >> 4;
    const int phase = blockIdx.y;
    const int pairIdx = blockIdx.x * 4 + (threadIdx.x >> 6);
    const int nPairs = (M + 31) >> 5;
    if (pairIdx >= nPairs) return;

    const int row0 = pairIdx * 32;
    const int rA0 = imin(row0 + m16, M - 1);
    const int rA1 = imin(row0 + 16 + m16, M - 1);

    s8v a0h[KS], a0l[KS], a1h[KS], a1l[KS];
#pragma unroll
    for (int ks = 0; ks < KS; ks++) {
        a0h[ks] = *(const s8v*)(ehi + (size_t)rA0 * DIM + ks * 32 + q4 * 8);
        a0l[ks] = *(const s8v*)(elo + (size_t)rA0 * DIM + ks * 32 + q4 * 8);
        a1h[ks] = *(const s8v*)(ehi + (size_t)rA1 * DIM + ks * 32 + q4 * 8);
        a1l[ks] = *(const s8v*)(elo + (size_t)rA1 * DIM + ks * 32 + q4 * 8);
    }

    f4v acc0[NTp], acc1[NTp];
#pragma unroll
    for (int nt = 0; nt < NTp; nt++) { acc0[nt] = (f4v){0,0,0,0}; acc1[nt] = (f4v){0,0,0,0}; }

#pragma unroll
    for (int ks = 0; ks < KS; ks++) {
#pragma unroll
        for (int nt = 0; nt < NTp; nt++) {
            s8v b = *(const s8v*)(wfrag + ((size_t)phase * FRp + (size_t)(nt * KS + ks) * 64 + lane) * 8);
            acc0[nt] = __builtin_amdgcn_mfma_f32_16x16x32_bf16(a0h[ks], b, acc0[nt], 0, 0, 0);
            acc0[nt] = __builtin_amdgcn_mfma_f32_16x16x32_bf16(a0l[ks], b, acc0[nt], 0, 0, 0);
            acc1[nt] = __builtin_amdgcn_mfma_f32_16x16x32_bf16(a1h[ks], b, acc1[nt], 0, 0, 0);
            acc1[nt] = __builtin_amdgcn_mfma_f32_16x16x32_bf16(a1l[ks], b, acc1[nt], 0, 0, 0);
        }
    }

#pragma unroll
    for (int nt = 0; nt < NTp; nt++) {
        const int col = phase * 128 + nt * 16 + m16;
        const float bias = b0[col];
#pragma unroll
        for (int r = 0; r < 4; r++) {
            const int gr0 = row0 + q4 * 4 + r;
            if (gr0 < M) Out[(size_t)gr0 * NOUT + col] = acc0[nt][r] + bias;
            const int gr1 = gr0 + 16;
            if (gr1 < M && row0 + 16 < M) Out[(size_t)gr1 * NOUT + col] = acc1[nt][r] + bias;
        }
    }
}

// ---------------------------------------------------------------------------
// Fused attention + residual + LayerNorm. One wave per node; lane owns dims
// (2*lane, 2*lane+1); head = lane>>3. 4-edge chunks, double-buffered prefetch.
// R-this: SCALAR gather addressing — lane l caches colIdx[win+l] (one
// coalesced load per <=64-edge window, avg deg 16 => usually one); per edge
// the column comes back via v_readlane into SGPR, so the KV row pointer is
// wave-uniform (saddr form, loop-invariant v_off = lane*8). Removes per-edge
// colIdx vector load + 64-bit VGPR address arithmetic from the VALU.
// ---------------------------------------------------------------------------
__global__ __launch_bounds__(256) void agg_k(
    const float* __restrict__ Q, const unsigned short* __restrict__ KV,
    const int* __restrict__ rowPtr, const int* __restrict__ colIdx,
    const float* __restrict__ ln_s, const float* __restrict__ ln_b,
    unsigned short* __restrict__ ehi, unsigned short* __restrict__ elo, int n)
{
    const int node = blockIdx.x * 4 + (threadIdx.x >> 6);
    if (node >= n) return;
    const int lane = threadIdx.x & 63;
    const int d = lane * 2;

    constexpr float LOG2E = 1.4426950408889634f;
    constexpr float CLAMP = 10.0f * LOG2E;   // clip(t,±10) in 2^x domain

    const float2 qraw = *(const float2*)(Q + (size_t)node * DIM + d);
    const float qx = qraw.x * LOG2E, qy = qraw.y * LOG2E;
    const unsigned int rh = *(const unsigned int*)(ehi + (size_t)node * DIM + d);
    const unsigned int rl = *(const unsigned int*)(elo + (size_t)node * DIM + d);
    const float r0 = bf2f(rh & 0xffffu) + bf2f(rl & 0xffffu);
    const float r1 = bf2f(rh >> 16) + bf2f(rl >> 16);

    const int e0 = rowPtr[node], e1 = rowPtr[node + 1];
    float acc0 = 0.f, acc1 = 0.f, den = 0.f;

    if (e1 > e0) {
        const uint2* KV2 = (const uint2*)KV;   // row = 64 uint2; lane l -> {K2l,V2l,K2l+1,V2l+1}
        const int emax = e1 - 1;
        int winBase = e0;
        int myIdx = colIdx[imin(e0 + lane, emax)];   // window cache: 64 future cols
        uint2 cA[4], cB[4];
        // reload window if chunk would step past the 64 cached entries
#define WINCHK(b_)                                                      \
        if ((b_) + 3 - winBase >= 64) {                                 \
            winBase = (b_);                                             \
            myIdx = colIdx[imin((b_) + lane, emax)];                    \
        }
#define LOADC(arr, b_)                                                  \
        {                                                               \
            WINCHK(b_)                                                  \
            _Pragma("unroll")                                           \
            for (int j = 0; j < 4; j++) {                               \
                int rel = __builtin_amdgcn_readfirstlane(               \
                    imin((b_) + j, emax) - winBase);                    \
                int cc = __builtin_amdgcn_readlane(myIdx, rel);         \
                const uint2* rp = KV2 + ((size_t)(unsigned)cc << 6);    \
                arr[j] = rp[lane];                                      \
            }                                                           \
        }
#define COMP(arr, base_)                                                \
        {                                                               \
            _Pragma("unroll")                                           \
            for (int j = 0; j < 4; j++) {                               \
                const unsigned int w0 = arr[j].x, w1 = arr[j].y;        \
                float p = qx * bf2f(w0 & 0xffffu)                       \
                        + qy * bf2f(w1 & 0xffffu);                      \
                p = dpp_add_f<0xB1>(p);   /* xor1 */                    \
                p = dpp_add_f<0x4E>(p);   /* xor2 */                    \
                p = dpp_add_f<0x141>(p);  /* ^7: other quad sum */      \
                p = fminf(fmaxf(p, -CLAMP), CLAMP);                     \
                float w = fast_exp2(p);                                 \
                w = ((base_) + j < e1) ? w : 0.f;                       \
                den += w;                                               \
                acc0 += w * bf2f_hi(w0);                                \
                acc1 += w * bf2f_hi(w1);                                \
            }                                                           \
        }
        int base = e0;
        LOADC(cA, base)
        while (true) {
            int nxt = base + 4;
            if (nxt < e1) LOADC(cB, nxt)
            COMP(cA, base)
            base = nxt;
            if (base >= e1) break;
            int nxt2 = base + 4;
            if (nxt2 < e1) LOADC(cA, nxt2)
            COMP(cB, base)
            base = nxt2;
            if (base >= e1) break;
        }
#undef LOADC
#undef COMP
#undef WINCHK
    }
    const float inv = 1.f / (den + 1e-8f);
    const float o0 = acc0 * inv + r0;
    const float o1 = acc1 * inv + r1;

    const float s  = wave_allsum(o0 + o1);
    const float s2 = wave_allsum(o0 * o0 + o1 * o1);
    const float mu = s * (1.f / 128.f);
    const float var = s2 * (1.f / 128.f) - mu * mu;
    const float rs = rsqrtf(var + 1e-6f);
    const float2 lns = *(const float2*)(ln_s + d);
    const float2 lnb = *(const float2*)(ln_b + d);
    const float y0 = (o0 - mu) * rs * lns.x + lnb.x;
    const float y1 = (o1 - mu) * rs * lns.y + lnb.y;
    const unsigned short h0 = f2bf(y0), h1 = f2bf(y1);
    const unsigned short l0 = f2bf(y0 - bf2f(h0)), l1 = f2bf(y1 - bf2f(h1));
    *(unsigned int*)(ehi + (size_t)node * DIM + d) = (unsigned int)h0 | ((unsigned int)h1 << 16);
    *(unsigned int*)(elo + (size_t)node * DIM + d) = (unsigned int)l0 | ((unsigned int)l1 << 16);
}

// ---------------------------------------------------------------------------
// Launch
// ---------------------------------------------------------------------------
extern "C" void kernel_launch(void* const* d_in, const int* in_sizes, int n_in,
                              void* d_out, int out_size, void* d_ws, size_t ws_size,
                              hipStream_t stream)
{
    const float* x    = (const float*)d_in[0];
    const void*  ei   = d_in[1];
    const float* Wp   = (const float*)d_in[2];
    const float* Wpb  = (const float*)d_in[3];
    const float* Wpos = (const float*)d_in[4];
    const float* q1   = (const float*)d_in[5];
    const float* k1   = (const float*)d_in[6];
    const float* v1   = (const float*)d_in[7];
    const float* l1s  = (const float*)d_in[8];
    const float* l1b  = (const float*)d_in[9];
    const float* q2   = (const float*)d_in[10];
    const float* k2   = (const float*)d_in[11];
    const float* v2   = (const float*)d_in[12];
    const float* l2s  = (const float*)d_in[13];
    const float* l2b  = (const float*)d_in[14];
    const float* invw = (const float*)d_in[15];
    const float* invb = (const float*)d_in[16];

    const int N = in_sizes[0] / 256;   // 50000
    const int E = in_sizes[1] / 2;     // 800000

    char* p = (char*)d_ws;
    auto carve = [&](size_t bytes) -> void* {
        void* r = (void*)p;
        p += (bytes + 255) & ~(size_t)255;
        return r;
    };
    unsigned short* ehi = (unsigned short*)carve((size_t)N * DIM * 2);
    unsigned short* elo = (unsigned short*)carve((size_t)N * DIM * 2);
    float*          Qb  = (float*)carve((size_t)N * DIM * 4);
    unsigned short* KVb = (unsigned short*)carve((size_t)N * 256 * 2);
    int*   deg    = (int*)carve((size_t)N * 4);
    int*   incl   = (int*)carve((size_t)N * 4);
    int*   blkS   = (int*)carve(1024);
    int*   rowPtr = (int*)carve((size_t)(N + 1) * 4);
    int*   cursor = (int*)carve((size_t)N * 4);
    int*   colIdx = (int*)carve((size_t)E * 4);
    int*   rc     = (int*)carve((size_t)2 * E * 4);
    unsigned short* wfragP    = (unsigned short*)carve((size_t)2 * 256 * 128 * 2);
    unsigned short* wfragQKV1 = (unsigned short*)carve((size_t)3 * 2 * 128 * 128 * 2);
    unsigned short* wfragQKV2 = (unsigned short*)carve((size_t)3 * 2 * 128 * 128 * 2);
    unsigned short* wfragO    = (unsigned short*)carve((size_t)128 * 256 * 2);

    int* rows = rc;
    int* cols = rc + E;

    const int nb  = (N + 255) / 256;
    const int ebl = (E + 255) / 256;
    const int nPairs = (N + 31) / 32;
    const dim3 ggrid((nPairs + 3) / 4, 2);
    const dim3 ggridP((nPairs + 3) / 4, 1);

    // CSR build (fused setup: dtype sniff + convert + degree count)
    hipMemsetAsync(deg, 0, (size_t)N * 4, stream);
    setup_k<<<(2 * E + 255) / 256, 256, 0, stream>>>(ei, 2 * E, E, rc, deg);
    scan1_k<<<nb, 256, 0, stream>>>(deg, N, incl, blkS);
    scan2_k<<<1, 256, 0, stream>>>(blkS, nb);
    scan3_k<<<nb, 256, 0, stream>>>(incl, deg, blkS, N, rowPtr, cursor);
    scatter_k<<<ebl, 256, 0, stream>>>(rows, cols, E, cursor, colIdx);

    // all weight fragments in one launch
    build_all_wfrag_k<<<144, 256, 0, stream>>>(Wp, q1, k1, v1, q2, k2, v2, invw,
                                               wfragP, wfragQKV1, wfragQKV2, wfragO);

    // input projection -> trunk planes (both phases fused; x read once)
    proj_k<<<ggridP, 256, 0, stream>>>(x, wfragP, Wpb, Wpos, ehi, elo, N);

    // layer 1
    qkv_k<<<ggrid, 256, 0, stream>>>(ehi, elo, wfragQKV1, Qb, KVb, N);
    agg_k<<<(N + 3) / 4, 256, 0, stream>>>(Qb, KVb, rowPtr, colIdx, l1s, l1b, ehi, elo, N);

    // layer 2
    qkv_k<<<ggrid, 256, 0, stream>>>(ehi, elo, wfragQKV2, Qb, KVb, N);
    agg_k<<<(N + 3) / 4, 256, 0, stream>>>(Qb, KVb, rowPtr, colIdx, l2s, l2b, ehi, elo, N);

    // output projection
    outproj_k<<<ggrid, 256, 0, stream>>>(ehi, elo, wfragO, invb, (float*)d_out, N);
}

// Round 4
// 483.748 us; speedup vs baseline: 1.0397x; 1.0052x over previous
//
#include <hip/hip_runtime.h>
#include <hip/hip_bf16.h>

#define HEADS 8
#define DIM 128

typedef short s8v __attribute__((ext_vector_type(8)));
typedef float f4v __attribute__((ext_vector_type(4)));

__device__ __forceinline__ float bf2f(unsigned int lo16) {
    union { unsigned int i; float f; } v; v.i = lo16 << 16; return v.f;
}
__device__ __forceinline__ float bf2f_hi(unsigned int w) {
    union { unsigned int i; float f; } v; v.i = w & 0xffff0000u; return v.f;
}
__device__ __forceinline__ unsigned short f2bf(float f) {
    __hip_bfloat16 h = __float2bfloat16(f);
    return *reinterpret_cast<unsigned short*>(&h);
}
__device__ __forceinline__ int imin(int a, int b) { return a < b ? a : b; }

// DPP butterfly add within 8-lane groups (head groups). CTRL must be imm.
// 0xB1 = quad_perm(1,0,3,2) = xor1; 0x4E = quad_perm(2,3,0,1) = xor2;
// 0x141 = row_half_mirror = lane^7 within each 8-lane half-row.
template<int CTRL>
__device__ __forceinline__ float dpp_add_f(float x) {
    int y = __builtin_amdgcn_update_dpp(0, __float_as_int(x), CTRL, 0xF, 0xF, true);
    return x + __int_as_float(y);
}

// Full-wave (64-lane) sum via classic GCN DPP ladder.
__device__ __forceinline__ float wave_allsum(float x) {
    x = dpp_add_f<0x111>(x);  // row_shr:1
    x = dpp_add_f<0x112>(x);  // row_shr:2
    x = dpp_add_f<0x114>(x);  // row_shr:4
    x = dpp_add_f<0x118>(x);  // row_shr:8
    x = dpp_add_f<0x142>(x);  // row_bcast:15
    x = dpp_add_f<0x143>(x);  // row_bcast:31
    return __int_as_float(__builtin_amdgcn_readlane(__float_as_int(x), 63));
}

#if __has_builtin(__builtin_amdgcn_exp2f)
#define fast_exp2(x) __builtin_amdgcn_exp2f(x)
#else
#define fast_exp2(x) __expf(0.6931471805599453f * (x))
#endif

// ---------------------------------------------------------------------------
// Fused setup: per-block dtype sniff (int64 vs int32) + edge convert + degree
// count. Every block redundantly sniffs the first 2 KB (validated logic, R2).
// ---------------------------------------------------------------------------
__global__ __launch_bounds__(256) void setup_k(const void* __restrict__ ei, int n2, int E,
                                               int* __restrict__ out, int* __restrict__ deg) {
    __shared__ int cnt;
    const unsigned int* w = (const unsigned int*)ei;
    if (threadIdx.x == 0) cnt = 0;
    __syncthreads();
    if (w[2 * threadIdx.x + 1] == 0u) atomicAdd(&cnt, 1);
    __syncthreads();
    const bool is64 = cnt > 192;
    int i = blockIdx.x * 256 + threadIdx.x;
    if (i < n2) {
        int v = is64 ? (int)((const long long*)ei)[i] : ((const int*)ei)[i];
        out[i] = v;
        if (i < E) atomicAdd(&deg[v], 1);   // rows half
    }
}

// ---------------------------------------------------------------------------
// CSR scan + scatter (validated in R2)
// ---------------------------------------------------------------------------
__global__ void scan1_k(const int* __restrict__ deg, int n,
                        int* __restrict__ incl, int* __restrict__ blkSums) {
    __shared__ int s[256];
    int i = blockIdx.x * 256 + threadIdx.x;
    int v = (i < n) ? deg[i] : 0;
    s[threadIdx.x] = v;
    __syncthreads();
    for (int off = 1; off < 256; off <<= 1) {
        int t = (threadIdx.x >= off) ? s[threadIdx.x - off] : 0;
        __syncthreads();
        s[threadIdx.x] += t;
        __syncthreads();
    }
    if (i < n) incl[i] = s[threadIdx.x];
    if (threadIdx.x == 255) blkSums[blockIdx.x] = s[255];
}

__global__ void scan2_k(int* __restrict__ blkSums, int nb) {
    __shared__ int s[256];
    int v = (threadIdx.x < nb) ? blkSums[threadIdx.x] : 0;
    s[threadIdx.x] = v;
    __syncthreads();
    for (int off = 1; off < 256; off <<= 1) {
        int t = (threadIdx.x >= off) ? s[threadIdx.x - off] : 0;
        __syncthreads();
        s[threadIdx.x] += t;
        __syncthreads();
    }
    if (threadIdx.x < nb) blkSums[threadIdx.x] = s[threadIdx.x] - v;
}

__global__ void scan3_k(const int* __restrict__ incl, const int* __restrict__ deg,
                        const int* __restrict__ blkOff, int n,
                        int* __restrict__ rowPtr, int* __restrict__ cursor) {
    int i = blockIdx.x * 256 + threadIdx.x;
    if (i < n) {
        int inc = incl[i] + blkOff[blockIdx.x];
        rowPtr[i + 1] = inc;
        cursor[i] = inc - deg[i];
    }
    if (i == 0) rowPtr[0] = 0;
}

__global__ void scatter_k(const int* __restrict__ rows, const int* __restrict__ cols, int E,
                          int* __restrict__ cursor, int* __restrict__ colIdx) {
    int e = blockIdx.x * 256 + threadIdx.x;
    if (e < E) {
        int pos = atomicAdd(&cursor[rows[e]], 1);
        colIdx[pos] = cols[e];
    }
}

// ---------------------------------------------------------------------------
// All weight-fragment builds in ONE kernel; job table by blockIdx.
// Frag f = (comp*split + p)*perPhase + (nt*KS + ks)*64 + lane; element j =
// W[ks*32 + (lane>>4)*8 + j][p*(Nd/split) + nt*16 + (lane&15)]. hi/lo bf16.
// ---------------------------------------------------------------------------
__global__ __launch_bounds__(256) void build_all_wfrag_k(
    const float* __restrict__ Wp, const float* __restrict__ q1, const float* __restrict__ k1,
    const float* __restrict__ v1, const float* __restrict__ q2, const float* __restrict__ k2,
    const float* __restrict__ v2, const float* __restrict__ invw,
    unsigned short* __restrict__ wfragP, unsigned short* __restrict__ wfragQKV1,
    unsigned short* __restrict__ wfragQKV2, unsigned short* __restrict__ wfragO)
{
    const int b = blockIdx.x;
    const float* W; unsigned short* dst; int Kd, Nd, ncomp, fb;
    const int split = 2;
    if (b < 32) { W = Wp; dst = wfragP; Kd = 256; Nd = 128; ncomp = 2; fb = b; }
    else if (b < 128) {
        int j = (b - 32) >> 4, r = (b - 32) & 15;
        const float* ws[6] = { q1, k1, v1, q2, k2, v2 };
        W = ws[j];
        dst = ((j < 3) ? wfragQKV1 : wfragQKV2) + (size_t)(j % 3) * 2 * 128 * 128;
        Kd = 128; Nd = 128; ncomp = 2; fb = r;
    } else { W = invw; dst = wfragO; Kd = 128; Nd = 256; ncomp = 1; fb = b - 128; }

    int f = fb * 256 + threadIdx.x;
    int KS = Kd >> 5;
    int perPhase = (Nd / 16 / split) * KS * 64;
    if (f >= ncomp * split * perPhase) return;
    int comp = f / (split * perPhase);
    int r1 = f - comp * split * perPhase;
    int p = r1 / perPhase;
    int r = r1 - p * perPhase;
    int nt = r / (KS * 64);
    int r2 = r - nt * KS * 64;
    int ks = r2 >> 6, lane = r2 & 63;
    int n = p * (Nd / split) + nt * 16 + (lane & 15);
    int k0 = ks * 32 + (lane >> 4) * 8;
    unsigned short tmp[8];
#pragma unroll
    for (int j = 0; j < 8; j++) {
        float w = W[(size_t)(k0 + j) * Nd + n];
        unsigned short hi = f2bf(w);
        tmp[j] = (comp == 0) ? hi : f2bf(w - bf2f(hi));
    }
#pragma unroll
    for (int j = 0; j < 8; j++) dst[(size_t)f * 8 + j] = tmp[j];
}

// ---------------------------------------------------------------------------
// Input projection (LDS-free): trunk planes = x(f32)[M,256] @ W_P + b + pos.
// Both 64-col phases fused into one pass (NT=8) so x is read ONCE.
// ---------------------------------------------------------------------------
__global__ __launch_bounds__(256) void proj_k(
    const float* __restrict__ A, const unsigned short* __restrict__ wfrag,
    const float* __restrict__ b0, const float* __restrict__ b1,
    unsigned short* __restrict__ ehi, unsigned short* __restrict__ elo, int M)
{
    constexpr int KD = 256, KS = 8, NT = 8;
    constexpr int FRp = 4 * KS * 64;  // 2048 frags per (comp,phase) plane
    const int lane = threadIdx.x & 63;
    const int m16 = lane & 15, q4 = lane >> 4;
    const int pairIdx = blockIdx.x * 4 + (threadIdx.x >> 6);
    const int nPairs = (M + 31) >> 5;
    if (pairIdx >= nPairs) return;

    const int row0 = pairIdx * 32;
    const int rA0 = imin(row0 + m16, M - 1);
    const int rA1 = imin(row0 + 16 + m16, M - 1);

    f4v acc0[NT], acc1[NT];
#pragma unroll
    for (int g = 0; g < NT; g++) { acc0[g] = (f4v){0,0,0,0}; acc1[g] = (f4v){0,0,0,0}; }

    for (int ks = 0; ks < KS; ks++) {
        const f4v* pa0 = (const f4v*)(A + (size_t)rA0 * KD + ks * 32 + q4 * 8);
        const f4v* pa1 = (const f4v*)(A + (size_t)rA1 * KD + ks * 32 + q4 * 8);
        f4v xa = pa0[0], xb = pa0[1], ya = pa1[0], yb = pa1[1];
        s8v a0h, a0l, a1h, a1l;
#pragma unroll
        for (int j = 0; j < 4; j++) {
            unsigned short h;
            h = f2bf(xa[j]); a0h[j] = (short)h; a0l[j] = (short)f2bf(xa[j] - bf2f(h));
            h = f2bf(xb[j]); a0h[4 + j] = (short)h; a0l[4 + j] = (short)f2bf(xb[j] - bf2f(h));
            h = f2bf(ya[j]); a1h[j] = (short)h; a1l[j] = (short)f2bf(ya[j] - bf2f(h));
            h = f2bf(yb[j]); a1h[4 + j] = (short)h; a1l[4 + j] = (short)f2bf(yb[j] - bf2f(h));
        }
#pragma unroll
        for (int g = 0; g < NT; g++) {
            const int p = g >> 2, nt = g & 3;
            const size_t fi = ((size_t)(nt * KS + ks) * 64 + lane) * 8;
            s8v bh = *(const s8v*)(wfrag + ((size_t)(0 * 2 + p) * FRp) * 8 + fi);
            s8v bl = *(const s8v*)(wfrag + ((size_t)(1 * 2 + p) * FRp) * 8 + fi);
            acc0[g] = __builtin_amdgcn_mfma_f32_16x16x32_bf16(a0h, bh, acc0[g], 0, 0, 0);
            acc0[g] = __builtin_amdgcn_mfma_f32_16x16x32_bf16(a0h, bl, acc0[g], 0, 0, 0);
            acc0[g] = __builtin_amdgcn_mfma_f32_16x16x32_bf16(a0l, bh, acc0[g], 0, 0, 0);
            acc1[g] = __builtin_amdgcn_mfma_f32_16x16x32_bf16(a1h, bh, acc1[g], 0, 0, 0);
            acc1[g] = __builtin_amdgcn_mfma_f32_16x16x32_bf16(a1h, bl, acc1[g], 0, 0, 0);
            acc1[g] = __builtin_amdgcn_mfma_f32_16x16x32_bf16(a1l, bh, acc1[g], 0, 0, 0);
        }
    }

#pragma unroll
    for (int g = 0; g < NT; g++) {
        const int col = g * 16 + m16;
        const float bias = b0[col] + b1[col];
#pragma unroll
        for (int r = 0; r < 4; r++) {
            const int gr0 = row0 + q4 * 4 + r;
            if (gr0 < M) {
                float v = acc0[g][r] + bias;
                unsigned short h = f2bf(v);
                ehi[(size_t)gr0 * DIM + col] = h;
                elo[(size_t)gr0 * DIM + col] = f2bf(v - bf2f(h));
            }
            const int gr1 = gr0 + 16;
            if (gr1 < M && row0 + 16 < M) {
                float v = acc1[g][r] + bias;
                unsigned short h = f2bf(v);
                ehi[(size_t)gr1 * DIM + col] = h;
                elo[(size_t)gr1 * DIM + col] = f2bf(v - bf2f(h));
            }
        }
    }
}

// ---------------------------------------------------------------------------
// Fused QKV (LDS-free): A = trunk planes. Q f32 (split-precision), K,V bf16.
// KV layout interleaved per-dim: KV[row][2d]=K[d], KV[row][2d+1]=V[d].
// grid (391,2).
// ---------------------------------------------------------------------------
__global__ __launch_bounds__(256) void qkv_k(
    const unsigned short* __restrict__ ehi, const unsigned short* __restrict__ elo,
    const unsigned short* __restrict__ wfrag,
    float* __restrict__ Qb, unsigned short* __restrict__ KVb, int M)
{
    constexpr int KS = 4, NTp = 4;
    constexpr int FRp = NTp * KS * 64;   // 1024
    constexpr int MATFR = 4 * FRp;       // 2 comp x 2 phase
    const int lane = threadIdx.x & 63;
    const int m16 = lane & 15, q4 = lane >> 4;
    const int phase = blockIdx.y;
    const int pairIdx = blockIdx.x * 4 + (threadIdx.x >> 6);
    const int nPairs = (M + 31) >> 5;
    if (pairIdx >= nPairs) return;

    const int row0 = pairIdx * 32;
    const int rA0 = imin(row0 + m16, M - 1);
    const int rA1 = imin(row0 + 16 + m16, M - 1);

    s8v a0h[KS], a0l[KS], a1h[KS], a1l[KS];
#pragma unroll
    for (int ks = 0; ks < KS; ks++) {
        a0h[ks] = *(const s8v*)(ehi + (size_t)rA0 * DIM + ks * 32 + q4 * 8);
        a0l[ks] = *(const s8v*)(elo + (size_t)rA0 * DIM + ks * 32 + q4 * 8);
        a1h[ks] = *(const s8v*)(ehi + (size_t)rA1 * DIM + ks * 32 + q4 * 8);
        a1l[ks] = *(const s8v*)(elo + (size_t)rA1 * DIM + ks * 32 + q4 * 8);
    }

    f4v aQ0[NTp], aQ1[NTp], aK0[NTp], aK1[NTp], aV0[NTp], aV1[NTp];
#pragma unroll
    for (int nt = 0; nt < NTp; nt++) {
        aQ0[nt] = (f4v){0,0,0,0}; aQ1[nt] = (f4v){0,0,0,0};
        aK0[nt] = (f4v){0,0,0,0}; aK1[nt] = (f4v){0,0,0,0};
        aV0[nt] = (f4v){0,0,0,0}; aV1[nt] = (f4v){0,0,0,0};
    }

#pragma unroll
    for (int ks = 0; ks < KS; ks++) {
#pragma unroll
        for (int nt = 0; nt < NTp; nt++) {
            const size_t fi = ((size_t)(nt * KS + ks) * 64 + lane) * 8;
            s8v qh = *(const s8v*)(wfrag + (size_t)(0 * MATFR + (0 * 2 + phase) * FRp) * 8 + fi);
            s8v ql = *(const s8v*)(wfrag + (size_t)(0 * MATFR + (1 * 2 + phase) * FRp) * 8 + fi);
            s8v kh = *(const s8v*)(wfrag + (size_t)(1 * MATFR + (0 * 2 + phase) * FRp) * 8 + fi);
            s8v kl = *(const s8v*)(wfrag + (size_t)(1 * MATFR + (1 * 2 + phase) * FRp) * 8 + fi);
            s8v vh = *(const s8v*)(wfrag + (size_t)(2 * MATFR + (0 * 2 + phase) * FRp) * 8 + fi);
            aQ0[nt] = __builtin_amdgcn_mfma_f32_16x16x32_bf16(a0h[ks], qh, aQ0[nt], 0, 0, 0);
            aQ0[nt] = __builtin_amdgcn_mfma_f32_16x16x32_bf16(a0h[ks], ql, aQ0[nt], 0, 0, 0);
            aQ0[nt] = __builtin_amdgcn_mfma_f32_16x16x32_bf16(a0l[ks], qh, aQ0[nt], 0, 0, 0);
            aQ1[nt] = __builtin_amdgcn_mfma_f32_16x16x32_bf16(a1h[ks], qh, aQ1[nt], 0, 0, 0);
            aQ1[nt] = __builtin_amdgcn_mfma_f32_16x16x32_bf16(a1h[ks], ql, aQ1[nt], 0, 0, 0);
            aQ1[nt] = __builtin_amdgcn_mfma_f32_16x16x32_bf16(a1l[ks], qh, aQ1[nt], 0, 0, 0);
            aK0[nt] = __builtin_amdgcn_mfma_f32_16x16x32_bf16(a0h[ks], kh, aK0[nt], 0, 0, 0);
            aK0[nt] = __builtin_amdgcn_mfma_f32_16x16x32_bf16(a0h[ks], kl, aK0[nt], 0, 0, 0);
            aK0[nt] = __builtin_amdgcn_mfma_f32_16x16x32_bf16(a0l[ks], kh, aK0[nt], 0, 0, 0);
            aK1[nt] = __builtin_amdgcn_mfma_f32_16x16x32_bf16(a1h[ks], kh, aK1[nt], 0, 0, 0);
            aK1[nt] = __builtin_amdgcn_mfma_f32_16x16x32_bf16(a1h[ks], kl, aK1[nt], 0, 0, 0);
            aK1[nt] = __builtin_amdgcn_mfma_f32_16x16x32_bf16(a1l[ks], kh, aK1[nt], 0, 0, 0);
            aV0[nt] = __builtin_amdgcn_mfma_f32_16x16x32_bf16(a0h[ks], vh, aV0[nt], 0, 0, 0);
            aV0[nt] = __builtin_amdgcn_mfma_f32_16x16x32_bf16(a0l[ks], vh, aV0[nt], 0, 0, 0);
            aV1[nt] = __builtin_amdgcn_mfma_f32_16x16x32_bf16(a1h[ks], vh, aV1[nt], 0, 0, 0);
            aV1[nt] = __builtin_amdgcn_mfma_f32_16x16x32_bf16(a1l[ks], vh, aV1[nt], 0, 0, 0);
        }
    }

#pragma unroll
    for (int nt = 0; nt < NTp; nt++) {
        const int col = phase * 64 + nt * 16 + m16;
#pragma unroll
        for (int r = 0; r < 4; r++) {
            const int gr0 = row0 + q4 * 4 + r;
            if (gr0 < M) {
                Qb[(size_t)gr0 * DIM + col] = aQ0[nt][r];
                *(unsigned int*)(KVb + (size_t)gr0 * 256 + 2 * col) =
                    (unsigned int)f2bf(aK0[nt][r]) | ((unsigned int)f2bf(aV0[nt][r]) << 16);
            }
            const int gr1 = gr0 + 16;
            if (gr1 < M && row0 + 16 < M) {
                Qb[(size_t)gr1 * DIM + col] = aQ1[nt][r];
                *(unsigned int*)(KVb + (size_t)gr1 * 256 + 2 * col) =
                    (unsigned int)f2bf(aK1[nt][r]) | ((unsigned int)f2bf(aV1[nt][r]) << 16);
            }
        }
    }
}

// ---------------------------------------------------------------------------
// Output projection (LDS-free): d_out(f32)[M,256] = trunk @ inv_w + inv_b.
// ---------------------------------------------------------------------------
__global__ __launch_bounds__(256) void outproj_k(
    const unsigned short* __restrict__ ehi, const unsigned short* __restrict__ elo,
    const unsigned short* __restrict__ wfrag, const float* __restrict__ b0,
    float* __restrict__ Out, int M)
{
    constexpr int KS = 4, NTp = 8, NOUT = 256;
    constexpr int FRp = NTp * KS * 64;  // 2048
    const int lane = threadIdx.x & 63;
    const int m16 = lane & 15, q4 = lane >> 4;
    const int phase = blockIdx.y;
    const int pairIdx = blockIdx.x * 4 + (threadIdx.x >> 6);
    const int nPairs = (M + 31) >> 5;
    if (pairIdx >= nPairs) return;

    const int row0 = pairIdx * 32;
    const int rA0 = imin(row0 + m16, M - 1);
    const int rA1 = imin(row0 + 16 + m16, M - 1);

    s8v a0h[KS], a0l[KS], a1h[KS], a1l[KS];
#pragma unroll
    for (int ks = 0; ks < KS; ks++) {
        a0h[ks] = *(const s8v*)(ehi + (size_t)rA0 * DIM + ks * 32 + q4 * 8);
        a0l[ks] = *(const s8v*)(elo + (size_t)rA0 * DIM + ks * 32 + q4 * 8);
        a1h[ks] = *(const s8v*)(ehi + (size_t)rA1 * DIM + ks * 32 + q4 * 8);
        a1l[ks] = *(const s8v*)(elo + (size_t)rA1 * DIM + ks * 32 + q4 * 8);
    }

    f4v acc0[NTp], acc1[NTp];
#pragma unroll
    for (int nt = 0; nt < NTp; nt++) { acc0[nt] = (f4v){0,0,0,0}; acc1[nt] = (f4v){0,0,0,0}; }

#pragma unroll
    for (int ks = 0; ks < KS; ks++) {
#pragma unroll
        for (int nt = 0; nt < NTp; nt++) {
            s8v b = *(const s8v*)(wfrag + ((size_t)phase * FRp + (size_t)(nt * KS + ks) * 64 + lane) * 8);
            acc0[nt] = __builtin_amdgcn_mfma_f32_16x16x32_bf16(a0h[ks], b, acc0[nt], 0, 0, 0);
            acc0[nt] = __builtin_amdgcn_mfma_f32_16x16x32_bf16(a0l[ks], b, acc0[nt], 0, 0, 0);
            acc1[nt] = __builtin_amdgcn_mfma_f32_16x16x32_bf16(a1h[ks], b, acc1[nt], 0, 0, 0);
            acc1[nt] = __builtin_amdgcn_mfma_f32_16x16x32_bf16(a1l[ks], b, acc1[nt], 0, 0, 0);
        }
    }

#pragma unroll
    for (int nt = 0; nt < NTp; nt++) {
        const int col = phase * 128 + nt * 16 + m16;
        const float bias = b0[col];
#pragma unroll
        for (int r = 0; r < 4; r++) {
            const int gr0 = row0 + q4 * 4 + r;
            if (gr0 < M) Out[(size_t)gr0 * NOUT + col] = acc0[nt][r] + bias;
            const int gr1 = gr0 + 16;
            if (gr1 < M && row0 + 16 < M) Out[(size_t)gr1 * NOUT + col] = acc1[nt][r] + bias;
        }
    }
}

// ---------------------------------------------------------------------------
// Fused attention + residual + LayerNorm. One wave per node; lane owns dims
// (2*lane, 2*lane+1); head = lane>>3. R-this: 8-edge chunks double-buffered
// -> 16 gathers in flight/wave (was 8) to cover random-gather latency
// (latency-bound diagnosis: VALU 65% / HBM 46% / occ 67% all mid-range).
// Window readlane addressing hoisted: rel0 once per chunk, rel0+j on SALU.
// __launch_bounds__(256,8) pins VGPR<=64 so occupancy can't drop.
// ---------------------------------------------------------------------------
__global__ __launch_bounds__(256, 8) void agg_k(
    const float* __restrict__ Q, const unsigned short* __restrict__ KV,
    const int* __restrict__ rowPtr, const int* __restrict__ colIdx,
    const float* __restrict__ ln_s, const float* __restrict__ ln_b,
    unsigned short* __restrict__ ehi, unsigned short* __restrict__ elo, int n)
{
    const int node = blockIdx.x * 4 + (threadIdx.x >> 6);
    if (node >= n) return;
    const int lane = threadIdx.x & 63;
    const int d = lane * 2;

    constexpr float LOG2E = 1.4426950408889634f;
    constexpr float CLAMP = 10.0f * LOG2E;   // clip(t,±10) in 2^x domain

    const float2 qraw = *(const float2*)(Q + (size_t)node * DIM + d);
    const float qx = qraw.x * LOG2E, qy = qraw.y * LOG2E;
    const unsigned int rh = *(const unsigned int*)(ehi + (size_t)node * DIM + d);
    const unsigned int rl = *(const unsigned int*)(elo + (size_t)node * DIM + d);
    const float r0 = bf2f(rh & 0xffffu) + bf2f(rl & 0xffffu);
    const float r1 = bf2f(rh >> 16) + bf2f(rl >> 16);

    const int e0 = rowPtr[node], e1 = rowPtr[node + 1];
    float acc0 = 0.f, acc1 = 0.f, den = 0.f;

    if (e1 > e0) {
        const uint2* KV2 = (const uint2*)KV;   // row = 64 uint2; lane l -> {K2l,V2l,K2l+1,V2l+1}
        const int emax = e1 - 1;
        int winBase = e0;
        int myIdx = colIdx[imin(e0 + lane, emax)];   // window cache: 64 future cols
        uint2 cA[8], cB[8];
        // reload window if chunk would step past the 64 cached entries.
        // After reload, rel = b_+j-winBase is in [0,7]; lanes past emax in the
        // window hold colIdx[emax] (valid row), so no per-edge clamp needed.
#define WINCHK(b_)                                                      \
        if ((b_) + 7 - winBase >= 64) {                                 \
            winBase = (b_);                                             \
            myIdx = colIdx[imin((b_) + lane, emax)];                    \
        }
#define LOADC(arr, b_)                                                  \
        {                                                               \
            WINCHK(b_)                                                  \
            const int rel0 = __builtin_amdgcn_readfirstlane((b_) - winBase); \
            _Pragma("unroll")                                           \
            for (int j = 0; j < 8; j++) {                               \
                int cc = __builtin_amdgcn_readlane(myIdx, rel0 + j);    \
                const uint2* rp = KV2 + ((size_t)(unsigned)cc << 6);    \
                arr[j] = rp[lane];                                      \
            }                                                           \
        }
#define COMP(arr, base_)                                                \
        {                                                               \
            _Pragma("unroll")                                           \
            for (int j = 0; j < 8; j++) {                               \
                const unsigned int w0 = arr[j].x, w1 = arr[j].y;        \
                float p = qx * bf2f(w0 & 0xffffu)                       \
                        + qy * bf2f(w1 & 0xffffu);                      \
                p = dpp_add_f<0xB1>(p);   /* xor1 */                    \
                p = dpp_add_f<0x4E>(p);   /* xor2 */                    \
                p = dpp_add_f<0x141>(p);  /* ^7: other quad sum */      \
                p = fminf(fmaxf(p, -CLAMP), CLAMP);                     \
                float w = fast_exp2(p);                                 \
                w = ((base_) + j < e1) ? w : 0.f;                       \
                den += w;                                               \
                acc0 += w * bf2f_hi(w0);                                \
                acc1 += w * bf2f_hi(w1);                                \
            }                                                           \
        }
        int base = e0;
        LOADC(cA, base)
        while (true) {
            int nxt = base + 8;
            if (nxt < e1) LOADC(cB, nxt)
            COMP(cA, base)
            base = nxt;
            if (base >= e1) break;
            int nxt2 = base + 8;
            if (nxt2 < e1) LOADC(cA, nxt2)
            COMP(cB, base)
            base = nxt2;
            if (base >= e1) break;
        }
#undef LOADC
#undef COMP
#undef WINCHK
    }
    const float inv = 1.f / (den + 1e-8f);
    const float o0 = acc0 * inv + r0;
    const float o1 = acc1 * inv + r1;

    const float s  = wave_allsum(o0 + o1);
    const float s2 = wave_allsum(o0 * o0 + o1 * o1);
    const float mu = s * (1.f / 128.f);
    const float var = s2 * (1.f / 128.f) - mu * mu;
    const float rs = rsqrtf(var + 1e-6f);
    const float2 lns = *(const float2*)(ln_s + d);
    const float2 lnb = *(const float2*)(ln_b + d);
    const float y0 = (o0 - mu) * rs * lns.x + lnb.x;
    const float y1 = (o1 - mu) * rs * lns.y + lnb.y;
    const unsigned short h0 = f2bf(y0), h1 = f2bf(y1);
    const unsigned short l0 = f2bf(y0 - bf2f(h0)), l1 = f2bf(y1 - bf2f(h1));
    *(unsigned int*)(ehi + (size_t)node * DIM + d) = (unsigned int)h0 | ((unsigned int)h1 << 16);
    *(unsigned int*)(elo + (size_t)node * DIM + d) = (unsigned int)l0 | ((unsigned int)l1 << 16);
}

// ---------------------------------------------------------------------------
// Launch
// ---------------------------------------------------------------------------
extern "C" void kernel_launch(void* const* d_in, const int* in_sizes, int n_in,
                              void* d_out, int out_size, void* d_ws, size_t ws_size,
                              hipStream_t stream)
{
    const float* x    = (const float*)d_in[0];
    const void*  ei   = d_in[1];
    const float* Wp   = (const float*)d_in[2];
    const float* Wpb  = (const float*)d_in[3];
    const float* Wpos = (const float*)d_in[4];
    const float* q1   = (const float*)d_in[5];
    const float* k1   = (const float*)d_in[6];
    const float* v1   = (const float*)d_in[7];
    const float* l1s  = (const float*)d_in[8];
    const float* l1b  = (const float*)d_in[9];
    const float* q2   = (const float*)d_in[10];
    const float* k2   = (const float*)d_in[11];
    const float* v2   = (const float*)d_in[12];
    const float* l2s  = (const float*)d_in[13];
    const float* l2b  = (const float*)d_in[14];
    const float* invw = (const float*)d_in[15];
    const float* invb = (const float*)d_in[16];

    const int N = in_sizes[0] / 256;   // 50000
    const int E = in_sizes[1] / 2;     // 800000

    char* p = (char*)d_ws;
    auto carve = [&](size_t bytes) -> void* {
        void* r = (void*)p;
        p += (bytes + 255) & ~(size_t)255;
        return r;
    };
    unsigned short* ehi = (unsigned short*)carve((size_t)N * DIM * 2);
    unsigned short* elo = (unsigned short*)carve((size_t)N * DIM * 2);
    float*          Qb  = (float*)carve((size_t)N * DIM * 4);
    unsigned short* KVb = (unsigned short*)carve((size_t)N * 256 * 2);
    int*   deg    = (int*)carve((size_t)N * 4);
    int*   incl   = (int*)carve((size_t)N * 4);
    int*   blkS   = (int*)carve(1024);
    int*   rowPtr = (int*)carve((size_t)(N + 1) * 4);
    int*   cursor = (int*)carve((size_t)N * 4);
    int*   colIdx = (int*)carve((size_t)E * 4);
    int*   rc     = (int*)carve((size_t)2 * E * 4);
    unsigned short* wfragP    = (unsigned short*)carve((size_t)2 * 256 * 128 * 2);
    unsigned short* wfragQKV1 = (unsigned short*)carve((size_t)3 * 2 * 128 * 128 * 2);
    unsigned short* wfragQKV2 = (unsigned short*)carve((size_t)3 * 2 * 128 * 128 * 2);
    unsigned short* wfragO    = (unsigned short*)carve((size_t)128 * 256 * 2);

    int* rows = rc;
    int* cols = rc + E;

    const int nb  = (N + 255) / 256;
    const int ebl = (E + 255) / 256;
    const int nPairs = (N + 31) / 32;
    const dim3 ggrid((nPairs + 3) / 4, 2);
    const dim3 ggridP((nPairs + 3) / 4, 1);

    // CSR build (fused setup: dtype sniff + convert + degree count)
    hipMemsetAsync(deg, 0, (size_t)N * 4, stream);
    setup_k<<<(2 * E + 255) / 256, 256, 0, stream>>>(ei, 2 * E, E, rc, deg);
    scan1_k<<<nb, 256, 0, stream>>>(deg, N, incl, blkS);
    scan2_k<<<1, 256, 0, stream>>>(blkS, nb);
    scan3_k<<<nb, 256, 0, stream>>>(incl, deg, blkS, N, rowPtr, cursor);
    scatter_k<<<ebl, 256, 0, stream>>>(rows, cols, E, cursor, colIdx);

    // all weight fragments in one launch
    build_all_wfrag_k<<<144, 256, 0, stream>>>(Wp, q1, k1, v1, q2, k2, v2, invw,
                                               wfragP, wfragQKV1, wfragQKV2, wfragO);

    // input projection -> trunk planes (both phases fused; x read once)
    proj_k<<<ggridP, 256, 0, stream>>>(x, wfragP, Wpb, Wpos, ehi, elo, N);

    // layer 1
    qkv_k<<<ggrid, 256, 0, stream>>>(ehi, elo, wfragQKV1, Qb, KVb, N);
    agg_k<<<(N + 3) / 4, 256, 0, stream>>>(Qb, KVb, rowPtr, colIdx, l1s, l1b, ehi, elo, N);

    // layer 2
    qkv_k<<<ggrid, 256, 0, stream>>>(ehi, elo, wfragQKV2, Qb, KVb, N);
    agg_k<<<(N + 3) / 4, 256, 0, stream>>>(Qb, KVb, rowPtr, colIdx, l2s, l2b, ehi, elo, N);

    // output projection
    outproj_k<<<ggrid, 256, 0, stream>>>(ehi, elo, wfragO, invb, (float*)d_out, N);
}